// Round 11
// baseline (11879.550 us; speedup 1.0000x reference)
//
#include <hip/hip_runtime.h>
#include <hip/hip_fp16.h>
#include <math.h>

namespace {
constexpr int kB = 16;
constexpr int kV = 500000;
constexpr int kF = 1000000;
constexpr float kEps = 1e-6f;
constexpr int kNB = (kV + 255) / 256;     // 1954
constexpr int kNR = 8;                    // vertex regions (v>>16; kV < 8*65536)

constexpr size_t kVtx16Uints = (size_t)kV * 32;    // 64 MB
constexpr size_t kFn16Uints  = (size_t)kF * 32;    // 128 MB
constexpr size_t kIncPairs   = 3 * (size_t)kF;     // 24 MB as uint2
constexpr size_t kIntWords   = (size_t)kV + (kV + 1) + kNB + 3 * (size_t)kF + kNR;
constexpr size_t kWs16 = (kVtx16Uints + kFn16Uints) * 4 + kIncPairs * 8 + kIntWords * 4; // ~232 MB
constexpr size_t kWsC  = ((size_t)kV + (kV + 1) + kNB + 3 * (size_t)kF) * 4;             // ~16 MB
}

typedef unsigned u32x4 __attribute__((ext_vector_type(4)));

// a*b - c*d unfused: degenerate faces cancel EXACTLY (matches numpy; the
// fp16-rounded coords of duplicate indices are identical, so e2 = -e1 and
// both products round identically). FMA contraction would leave ulp noise
// that normalization amplifies to O(1).
__device__ __forceinline__ float cross_comp(float a, float b, float c, float d) {
    return __fsub_rn(__fmul_rn(a, b), __fmul_rn(c, d));
}

__device__ __forceinline__ unsigned pack2(float a, float b) {
    __half2 h = __halves2half2(__float2half_rn(a), __float2half_rn(b));
    return __builtin_bit_cast(unsigned, h);
}
__device__ __forceinline__ float2 unpack2(unsigned u) {
    return __half22float2(__builtin_bit_cast(__half2, u));
}

// Stage 64 records/wave (8 KB) in LDS, then write out so every store
// instruction covers FULL 128 B lines (1 KB contiguous per wave iteration)
// -> no RFO. NT (ext-vector) stores keep the streams out of L3 so the
// gather tables stay resident for the following pass.
__device__ __forceinline__ void staged_record_write(
    uint4 lds[4][64][8], const uint4 q[8], uint4* __restrict__ dstBase,
    size_t baseRec, int maxRec, int wave, int lane)
{
#pragma unroll
    for (int k = 0; k < 8; ++k)
        lds[wave][lane][(k + lane) & 7] = q[k];
    __syncthreads();
    uint4* dst = dstBase + baseRec * 8;
#pragma unroll
    for (int k = 0; k < 8; ++k) {
        int g = k * 64 + lane;          // uint4 index within wave's 8 KB
        int r = g >> 3, w = g & 7;
        if (baseRec + (size_t)r < (size_t)maxRec) {
            uint4 val = lds[wave][r][(w + r) & 7];
            u32x4 nv; nv.x = val.x; nv.y = val.y; nv.z = val.z; nv.w = val.w;
            __builtin_nontemporal_store(nv, reinterpret_cast<u32x4*>(&dst[g]));
        }
    }
}

// ---------- CSR build (bitwise-deterministic end state) ----------

__global__ __launch_bounds__(256) void zero_count_kernel(int* __restrict__ count) {
    int i = blockIdx.x * 256 + threadIdx.x;
    if (i < kV) count[i] = 0;
}

__global__ __launch_bounds__(256) void count_kernel(
    const int* __restrict__ faces, int* __restrict__ count)
{
    int i = blockIdx.x * 256 + threadIdx.x;
    if (i >= 3 * kF) return;
    atomicAdd(&count[faces[i]], 1);
}

__device__ __forceinline__ int block_incl_scan256(int x, int* lds) {
    int lane = threadIdx.x & 63;
    int wave = threadIdx.x >> 6;
    for (int d = 1; d < 64; d <<= 1) {
        int y = __shfl_up(x, d, 64);
        if (lane >= d) x += y;
    }
    if (lane == 63) lds[wave] = x;
    __syncthreads();
    int add = 0;
    for (int w = 0; w < wave; ++w) add += lds[w];
    __syncthreads();
    return x + add;
}

__global__ __launch_bounds__(256) void scan_block_kernel(
    const int* __restrict__ count, int* __restrict__ offs,
    int* __restrict__ blockSums)
{
    __shared__ int lds[4];
    int i = blockIdx.x * 256 + threadIdx.x;
    int x = (i < kV) ? count[i] : 0;
    int incl = block_incl_scan256(x, lds);
    if (i < kV) offs[i] = incl - x;
    if (threadIdx.x == 255) blockSums[blockIdx.x] = incl;
}

__global__ __launch_bounds__(256) void scan_sums_kernel(int* __restrict__ blockSums) {
    __shared__ int lds[4];
    __shared__ int carry;
    if (threadIdx.x == 0) carry = 0;
    __syncthreads();
    for (int base = 0; base < kNB; base += 256) {
        int i = base + threadIdx.x;
        int x = (i < kNB) ? blockSums[i] : 0;
        int incl = block_incl_scan256(x, lds);
        int c = carry;
        __syncthreads();
        if (i < kNB) blockSums[i] = incl - x + c;
        if (threadIdx.x == 255) carry = c + incl;
        __syncthreads();
    }
}

__global__ __launch_bounds__(256) void add_offsets_kernel(
    int* __restrict__ offs, const int* __restrict__ blockSums)
{
    int i = blockIdx.x * 256 + threadIdx.x;
    if (i < kV) offs[i] += blockSums[i >> 8];
    if (i == kV) offs[kV] = 3 * kF;
}

// Pass A: bucket incidences by vertex region. Bucket r occupies
// inc[offs[r<<16] .. offs[min((r+1)<<16,kV)]) — boundaries come free from
// the prefix sum. Appends via per-region counters; bucket CONTENT is a
// deterministic multiset (order canonicalized later by sort_rows).
__global__ __launch_bounds__(256) void bucket_kernel(
    const int* __restrict__ faces, const int* __restrict__ offs,
    int* __restrict__ rfill, uint2* __restrict__ inc)
{
    int i = blockIdx.x * 256 + threadIdx.x;
    if (i >= 3 * kF) return;
    int v = faces[i];
    int f = i / 3;
    int r = v >> 16;
    int idx = atomicAdd(&rfill[r], 1);
    int base = offs[r << 16];
    inc[(size_t)base + idx] = make_uint2((unsigned)v, (unsigned)f);
}

// Pass B: drain one region's bucket. All adj/count writes land in a
// ~1.5 MB slice -> lines collect all slot-writes while L2-resident ->
// writeback ~12 MB total instead of 3M x 64 B sectors. One launch per
// region bounds each line's fill window.
__global__ __launch_bounds__(256) void fill_from_bucket_kernel(
    const uint2* __restrict__ inc, const int* __restrict__ offs,
    int* __restrict__ count, int* __restrict__ adj, int r)
{
    int lo = r << 16;
    int hi = (r + 1) << 16; if (hi > kV) hi = kV;
    int base = offs[lo], end = offs[hi];
    int j = blockIdx.x * 256 + threadIdx.x;
    if (base + j >= end) return;
    uint2 e = inc[(size_t)base + j];
    int v = (int)e.x, f = (int)e.y;
    int old = atomicSub(&count[v], 1);
    adj[offs[v] + old - 1] = f;
}

// canonicalize slot order -> bitwise-deterministic adj -> deterministic fp sums
__global__ __launch_bounds__(256) void sort_rows_kernel(
    const int* __restrict__ offs, int* __restrict__ adj)
{
    int v = blockIdx.x * 256 + threadIdx.x;
    if (v >= kV) return;
    int s = offs[v], e = offs[v + 1];
    for (int i = s + 1; i < e; ++i) {
        int key = adj[i];
        int j = i - 1;
        while (j >= s && adj[j] > key) { adj[j + 1] = adj[j]; --j; }
        adj[j + 1] = key;
    }
}

// ---------- fp16-record path ----------

// verts [B][V][3] -> vtx16 [V][32u]; staged full-line NT writes.
__global__ __launch_bounds__(256) void transpose_kernel16(
    const float* __restrict__ verts, unsigned* __restrict__ vtx16)
{
    __shared__ uint4 lds[4][64][8];
    int tid = threadIdx.x;
    int wave = tid >> 6, lane = tid & 63;
    int v = blockIdx.x * 256 + tid;
    bool valid = v < kV;

    float o[48];
#pragma unroll
    for (int i = 0; i < 48; ++i) o[i] = 0.f;
    if (valid) {
#pragma unroll
        for (int b = 0; b < kB; ++b) {
            const float* p = verts + ((size_t)b * kV + v) * 3;
            o[3 * b + 0] = p[0];
            o[3 * b + 1] = p[1];
            o[3 * b + 2] = p[2];
        }
    }
    uint4 q[8];
#pragma unroll
    for (int k = 0; k < 6; ++k)
        q[k] = make_uint4(pack2(o[8 * k + 0], o[8 * k + 1]),
                          pack2(o[8 * k + 2], o[8 * k + 3]),
                          pack2(o[8 * k + 4], o[8 * k + 5]),
                          pack2(o[8 * k + 6], o[8 * k + 7]));
    q[6] = make_uint4(0u, 0u, 0u, 0u);
    q[7] = make_uint4(0u, 0u, 0u, 0u);

    size_t baseRec = (size_t)blockIdx.x * 256 + wave * 64;
    staged_record_write(lds, q, reinterpret_cast<uint4*>(vtx16),
                        baseRec, kV, wave, lane);
}

// Per face: 3 ONE-granule record gathers, 16 fp32 crosses from fp16 coords,
// areas (coalesced full lines, NT), fn16 via staged full-line NT writes.
__global__ __launch_bounds__(256) void face_kernel16(
    const unsigned* __restrict__ vtx16, const int* __restrict__ faces,
    unsigned* __restrict__ fn16, float* __restrict__ areas)
{
    __shared__ uint4 lds[4][64][8];
    int tid = threadIdx.x;
    int wave = tid >> 6, lane = tid & 63;
    int f = blockIdx.x * 256 + tid;
    bool valid = f < kF;

    float o[48];
#pragma unroll
    for (int i = 0; i < 48; ++i) o[i] = 0.f;

    if (valid) {
        int i0 = faces[3 * f + 0];
        int i1 = faces[3 * f + 1];
        int i2 = faces[3 * f + 2];
        const uint4* r0 = reinterpret_cast<const uint4*>(vtx16 + (size_t)i0 * 32);
        const uint4* r1 = reinterpret_cast<const uint4*>(vtx16 + (size_t)i1 * 32);
        const uint4* r2 = reinterpret_cast<const uint4*>(vtx16 + (size_t)i2 * 32);
#pragma unroll
        for (int g = 0; g < 2; ++g) {      // 8 batches per group (VGPR control)
            float A[24], B[24], C[24];
#pragma unroll
            for (int k = 0; k < 3; ++k) {
                uint4 ua = r0[3 * g + k], ub = r1[3 * g + k], uc = r2[3 * g + k];
                float2 t;
                t = unpack2(ua.x); A[8 * k + 0] = t.x; A[8 * k + 1] = t.y;
                t = unpack2(ua.y); A[8 * k + 2] = t.x; A[8 * k + 3] = t.y;
                t = unpack2(ua.z); A[8 * k + 4] = t.x; A[8 * k + 5] = t.y;
                t = unpack2(ua.w); A[8 * k + 6] = t.x; A[8 * k + 7] = t.y;
                t = unpack2(ub.x); B[8 * k + 0] = t.x; B[8 * k + 1] = t.y;
                t = unpack2(ub.y); B[8 * k + 2] = t.x; B[8 * k + 3] = t.y;
                t = unpack2(ub.z); B[8 * k + 4] = t.x; B[8 * k + 5] = t.y;
                t = unpack2(ub.w); B[8 * k + 6] = t.x; B[8 * k + 7] = t.y;
                t = unpack2(uc.x); C[8 * k + 0] = t.x; C[8 * k + 1] = t.y;
                t = unpack2(uc.y); C[8 * k + 2] = t.x; C[8 * k + 3] = t.y;
                t = unpack2(uc.z); C[8 * k + 4] = t.x; C[8 * k + 5] = t.y;
                t = unpack2(uc.w); C[8 * k + 6] = t.x; C[8 * k + 7] = t.y;
            }
#pragma unroll
            for (int bb = 0; bb < 8; ++bb) {
                float x0 = A[3 * bb], y0 = A[3 * bb + 1], z0 = A[3 * bb + 2];
                float x1 = B[3 * bb], y1 = B[3 * bb + 1], z1 = B[3 * bb + 2];
                float x2 = C[3 * bb], y2 = C[3 * bb + 1], z2 = C[3 * bb + 2];
                float e1x = x1 - x0, e1y = y1 - y0, e1z = z1 - z0;
                float e2x = x2 - x1, e2y = y2 - y1, e2z = z2 - z1;
                float nx = cross_comp(e1y, e2z, e1z, e2y);
                float ny = cross_comp(e1z, e2x, e1x, e2z);
                float nz = cross_comp(e1x, e2y, e1y, e2x);
                int bi = 8 * g + bb;
                o[3 * bi + 0] = nx;
                o[3 * bi + 1] = ny;
                o[3 * bi + 2] = nz;
                // wave writes 256 B contiguous per bi -> full lines, no RFO
                __builtin_nontemporal_store(
                    0.5f * sqrtf(nx * nx + ny * ny + nz * nz),
                    &areas[(size_t)bi * kF + f]);
            }
        }
    }

    uint4 q[8];
#pragma unroll
    for (int k = 0; k < 6; ++k)
        q[k] = make_uint4(pack2(o[8 * k + 0], o[8 * k + 1]),
                          pack2(o[8 * k + 2], o[8 * k + 3]),
                          pack2(o[8 * k + 4], o[8 * k + 5]),
                          pack2(o[8 * k + 6], o[8 * k + 7]));
    q[6] = make_uint4(0u, 0u, 0u, 0u);
    q[7] = make_uint4(0u, 0u, 0u, 0u);

    size_t baseRec = (size_t)blockIdx.x * 256 + wave * 64;
    staged_record_write(lds, q, reinterpret_cast<uint4*>(fn16),
                        baseRec, kF, wave, lane);
}

// Per vertex: walk sorted CSR, ONE-granule fn16 gathers (all 16 batches),
// fp32 accumulate, normalize, NT store.
__global__ __launch_bounds__(256) void vertex_kernel16(
    const unsigned* __restrict__ fn16, const int* __restrict__ offs,
    const int* __restrict__ adj, float* __restrict__ out)
{
    int v = blockIdx.x * 256 + threadIdx.x;
    if (v >= kV) return;
    int s = offs[v], e = offs[v + 1];

    float acc[48];
#pragma unroll
    for (int i = 0; i < 48; ++i) acc[i] = 0.f;

    for (int j = s; j < e; ++j) {
        const uint4* q = reinterpret_cast<const uint4*>(fn16 + (size_t)adj[j] * 32);
        uint4 w[6];
#pragma unroll
        for (int k = 0; k < 6; ++k) w[k] = q[k];
#pragma unroll
        for (int k = 0; k < 6; ++k) {
            float2 t0 = unpack2(w[k].x), t1 = unpack2(w[k].y);
            float2 t2 = unpack2(w[k].z), t3 = unpack2(w[k].w);
            acc[8 * k + 0] += t0.x; acc[8 * k + 1] += t0.y;
            acc[8 * k + 2] += t1.x; acc[8 * k + 3] += t1.y;
            acc[8 * k + 4] += t2.x; acc[8 * k + 5] += t2.y;
            acc[8 * k + 6] += t3.x; acc[8 * k + 7] += t3.y;
        }
    }

#pragma unroll
    for (int bi = 0; bi < kB; ++bi) {
        float x = acc[3 * bi], y = acc[3 * bi + 1], z = acc[3 * bi + 2];
        float n = sqrtf(x * x + y * y + z * z);
        float inv = 1.0f / fmaxf(n, kEps);
        size_t o = ((size_t)bi * kV + v) * 3;
        __builtin_nontemporal_store(x * inv, &out[o + 0]);
        __builtin_nontemporal_store(y * inv, &out[o + 1]);
        __builtin_nontemporal_store(z * inv, &out[o + 2]);
    }
}

// ---------- R3 fallback (ws >= 16 MB) ----------

__global__ __launch_bounds__(256) void fill_adj_kernel(
    const int* __restrict__ faces, const int* __restrict__ offs,
    int* __restrict__ count, int* __restrict__ adj)
{
    int i = blockIdx.x * 256 + threadIdx.x;
    if (i >= 3 * kF) return;
    int v = faces[i];
    int f = i / 3;
    int old = atomicSub(&count[v], 1);
    adj[offs[v] + old - 1] = f;
}

__global__ __launch_bounds__(256) void area_kernel_orig(
    const float* __restrict__ verts, const int* __restrict__ faces,
    float* __restrict__ areas)
{
    int f = blockIdx.x * 256 + threadIdx.x;
    if (f >= kF) return;
    int i0 = faces[3 * f + 0];
    int i1 = faces[3 * f + 1];
    int i2 = faces[3 * f + 2];
    size_t o0 = 3 * (size_t)i0, o1 = 3 * (size_t)i1, o2 = 3 * (size_t)i2;
#pragma unroll
    for (int b = 0; b < kB; ++b) {
        const float* vb = verts + (size_t)b * kV * 3;
        float x0 = vb[o0], y0 = vb[o0 + 1], z0 = vb[o0 + 2];
        float x1 = vb[o1], y1 = vb[o1 + 1], z1 = vb[o1 + 2];
        float x2 = vb[o2], y2 = vb[o2 + 1], z2 = vb[o2 + 2];
        float e1x = x1 - x0, e1y = y1 - y0, e1z = z1 - z0;
        float e2x = x2 - x1, e2y = y2 - y1, e2z = z2 - z1;
        float nx = cross_comp(e1y, e2z, e1z, e2y);
        float ny = cross_comp(e1z, e2x, e1x, e2z);
        float nz = cross_comp(e1x, e2y, e1y, e2x);
        areas[(size_t)b * kF + f] = 0.5f * sqrtf(nx * nx + ny * ny + nz * nz);
    }
}

__global__ __launch_bounds__(256) void gather_normalize_orig(
    const float* __restrict__ verts, const int* __restrict__ faces,
    const int* __restrict__ offs, const int* __restrict__ adj,
    float* __restrict__ out)
{
    int v = blockIdx.x * 256 + threadIdx.x;
    if (v >= kV) return;
    int s = offs[v], e = offs[v + 1];
    float ax[kB], ay[kB], az[kB];
#pragma unroll
    for (int b = 0; b < kB; ++b) { ax[b] = 0.f; ay[b] = 0.f; az[b] = 0.f; }
    for (int j = s; j < e; ++j) {
        int f = adj[j];
        int i0 = faces[3 * f + 0];
        int i1 = faces[3 * f + 1];
        int i2 = faces[3 * f + 2];
        size_t o0 = 3 * (size_t)i0, o1 = 3 * (size_t)i1, o2 = 3 * (size_t)i2;
#pragma unroll
        for (int b = 0; b < kB; ++b) {
            const float* vb = verts + (size_t)b * kV * 3;
            float x0 = vb[o0], y0 = vb[o0 + 1], z0 = vb[o0 + 2];
            float x1 = vb[o1], y1 = vb[o1 + 1], z1 = vb[o1 + 2];
            float x2 = vb[o2], y2 = vb[o2 + 1], z2 = vb[o2 + 2];
            float e1x = x1 - x0, e1y = y1 - y0, e1z = z1 - z0;
            float e2x = x2 - x1, e2y = y2 - y1, e2z = z2 - z1;
            ax[b] += cross_comp(e1y, e2z, e1z, e2y);
            ay[b] += cross_comp(e1z, e2x, e1x, e2z);
            az[b] += cross_comp(e1x, e2y, e1y, e2x);
        }
    }
#pragma unroll
    for (int b = 0; b < kB; ++b) {
        float n = sqrtf(ax[b] * ax[b] + ay[b] * ay[b] + az[b] * az[b]);
        float inv = 1.0f / fmaxf(n, kEps);
        size_t o = ((size_t)b * kV + v) * 3;
        out[o + 0] = ax[b] * inv;
        out[o + 1] = ay[b] * inv;
        out[o + 2] = az[b] * inv;
    }
}

// ---------- R1 fallback ----------

__global__ __launch_bounds__(256) void face_normals_atomic_kernel(
    const float* __restrict__ verts, const int* __restrict__ faces,
    float* __restrict__ vnorm, float* __restrict__ areas)
{
    long long tid = (long long)blockIdx.x * blockDim.x + threadIdx.x;
    if (tid >= (long long)kB * kF) return;
    int f = (int)(tid % kF);
    int b = (int)(tid / kF);
    int i0 = faces[3 * f + 0], i1 = faces[3 * f + 1], i2 = faces[3 * f + 2];
    const float* vb = verts + (size_t)b * kV * 3;
    size_t o0 = 3 * (size_t)i0, o1 = 3 * (size_t)i1, o2 = 3 * (size_t)i2;
    float x0 = vb[o0], y0 = vb[o0 + 1], z0 = vb[o0 + 2];
    float x1 = vb[o1], y1 = vb[o1 + 1], z1 = vb[o1 + 2];
    float x2 = vb[o2], y2 = vb[o2 + 1], z2 = vb[o2 + 2];
    float e1x = x1 - x0, e1y = y1 - y0, e1z = z1 - z0;
    float e2x = x2 - x1, e2y = y2 - y1, e2z = z2 - z1;
    float nx = cross_comp(e1y, e2z, e1z, e2y);
    float ny = cross_comp(e1z, e2x, e1x, e2z);
    float nz = cross_comp(e1x, e2y, e1y, e2x);
    float* vn = vnorm + (size_t)b * kV * 3;
    unsafeAtomicAdd(&vn[o0 + 0], nx); unsafeAtomicAdd(&vn[o0 + 1], ny); unsafeAtomicAdd(&vn[o0 + 2], nz);
    unsafeAtomicAdd(&vn[o1 + 0], nx); unsafeAtomicAdd(&vn[o1 + 1], ny); unsafeAtomicAdd(&vn[o1 + 2], nz);
    unsafeAtomicAdd(&vn[o2 + 0], nx); unsafeAtomicAdd(&vn[o2 + 1], ny); unsafeAtomicAdd(&vn[o2 + 2], nz);
    areas[(size_t)b * kF + f] = 0.5f * sqrtf(nx * nx + ny * ny + nz * nz);
}

__global__ __launch_bounds__(256) void normalize_inplace_kernel(float* __restrict__ vnorm) {
    long long tid = (long long)blockIdx.x * blockDim.x + threadIdx.x;
    if (tid >= (long long)kB * kV) return;
    size_t o = 3 * (size_t)tid;
    float x = vnorm[o], y = vnorm[o + 1], z = vnorm[o + 2];
    float n = sqrtf(x * x + y * y + z * z);
    float inv = 1.0f / fmaxf(n, kEps);
    vnorm[o] = x * inv; vnorm[o + 1] = y * inv; vnorm[o + 2] = z * inv;
}

// ---------- launch ----------

static void build_csr_bucketed(const int* faces, int* count, int* offs,
                               int* blockSums, int* rfill, uint2* inc,
                               int* adj, hipStream_t stream) {
    int gInc = (3 * kF + 255) / 256;
    zero_count_kernel<<<kNB, 256, 0, stream>>>(count);
    (void)hipMemsetAsync(rfill, 0, kNR * sizeof(int), stream);
    count_kernel<<<gInc, 256, 0, stream>>>(faces, count);
    scan_block_kernel<<<kNB, 256, 0, stream>>>(count, offs, blockSums);
    scan_sums_kernel<<<1, 256, 0, stream>>>(blockSums);
    add_offsets_kernel<<<(kV + 1 + 255) / 256, 256, 0, stream>>>(offs, blockSums);
    bucket_kernel<<<gInc, 256, 0, stream>>>(faces, offs, rfill, inc);
    for (int r = 0; r < kNR; ++r)
        fill_from_bucket_kernel<<<gInc, 256, 0, stream>>>(inc, offs, count, adj, r);
    sort_rows_kernel<<<kNB, 256, 0, stream>>>(offs, adj);
}

static void build_csr(const int* faces, int* count, int* offs, int* blockSums,
                      int* adj, hipStream_t stream) {
    int gInc = (3 * kF + 255) / 256;
    zero_count_kernel<<<kNB, 256, 0, stream>>>(count);
    count_kernel<<<gInc, 256, 0, stream>>>(faces, count);
    scan_block_kernel<<<kNB, 256, 0, stream>>>(count, offs, blockSums);
    scan_sums_kernel<<<1, 256, 0, stream>>>(blockSums);
    add_offsets_kernel<<<(kV + 1 + 255) / 256, 256, 0, stream>>>(offs, blockSums);
    fill_adj_kernel<<<gInc, 256, 0, stream>>>(faces, offs, count, adj);
    sort_rows_kernel<<<kNB, 256, 0, stream>>>(offs, adj);
}

extern "C" void kernel_launch(void* const* d_in, const int* in_sizes, int n_in,
                              void* d_out, int out_size, void* d_ws, size_t ws_size,
                              hipStream_t stream) {
    const float* verts = (const float*)d_in[0];
    const int*   faces = (const int*)d_in[1];

    float* out   = (float*)d_out;
    float* vecs  = out;                               // B*V*3
    float* areas = out + (size_t)kB * kV * 3;         // B*F

    int gF = (kF + 255) / 256;

    if (ws_size >= kWs16) {
        unsigned* vtx16 = (unsigned*)d_ws;                    // 64 MB
        unsigned* fn16  = vtx16 + kVtx16Uints;                // 128 MB
        uint2*    inc   = (uint2*)(fn16 + kFn16Uints);        // 24 MB
        int* count     = (int*)(inc + kIncPairs);
        int* offs      = count + kV;
        int* blockSums = offs + (kV + 1);
        int* adj       = blockSums + kNB;
        int* rfill     = adj + 3 * (size_t)kF;

        build_csr_bucketed(faces, count, offs, blockSums, rfill, inc, adj, stream);
        transpose_kernel16<<<kNB, 256, 0, stream>>>(verts, vtx16);
        face_kernel16<<<gF, 256, 0, stream>>>(vtx16, faces, fn16, areas);
        vertex_kernel16<<<kNB, 256, 0, stream>>>(fn16, offs, adj, vecs);
    } else if (ws_size >= kWsC) {
        int* count     = (int*)d_ws;
        int* offs      = count + kV;
        int* blockSums = offs + (kV + 1);
        int* adj       = blockSums + kNB;

        build_csr(faces, count, offs, blockSums, adj, stream);
        area_kernel_orig<<<gF, 256, 0, stream>>>(verts, faces, areas);
        gather_normalize_orig<<<kNB, 256, 0, stream>>>(verts, faces, offs, adj, vecs);
    } else {
        (void)hipMemsetAsync(vecs, 0, (size_t)kB * kV * 3 * sizeof(float), stream);
        long long nf = (long long)kB * kF;
        face_normals_atomic_kernel<<<(int)((nf + 255) / 256), 256, 0, stream>>>(verts, faces, vecs, areas);
        long long nv = (long long)kB * kV;
        normalize_inplace_kernel<<<(int)((nv + 255) / 256), 256, 0, stream>>>(vecs);
    }
}

// Round 12
// 687.509 us; speedup vs baseline: 17.2791x; 17.2791x over previous
//
#include <hip/hip_runtime.h>
#include <hip/hip_fp16.h>
#include <math.h>

namespace {
constexpr int kB = 16;
constexpr int kHalfB = 8;
constexpr int kV = 500000;
constexpr int kF = 1000000;
constexpr float kEps = 1e-6f;
constexpr int kNB = (kV + 255) / 256;     // 1954
constexpr int kNSweep = 4;                // fill sweeps; v>>17 in 0..3

// vtx8: [V] records of 16 uints (12 used = 24 fp16, pad to ONE 64 B sector)
// fn8 : [F] records of 16 uints (12 used = 24 fp16, pad to ONE 64 B sector)
constexpr size_t kVtx8Uints = (size_t)kV * 16;     // 32 MB
constexpr size_t kFn8Uints  = (size_t)kF * 16;     // 64 MB
constexpr size_t kIntBytes  = ((size_t)kV + (kV + 1) + kNB + 3 * (size_t)kF) * 4;
constexpr size_t kWsHalf16 = (kVtx8Uints + kFn8Uints) * 4 + kIntBytes;  // ~112 MB
constexpr size_t kWsC      = kIntBytes;                                 // ~16 MB
}

// a*b - c*d unfused: degenerate faces cancel EXACTLY (matches numpy; the
// fp16-rounded coords of duplicate indices are identical, so e2 = -e1 and
// both products round identically). FMA contraction would leave ulp noise
// that normalization amplifies to O(1).
__device__ __forceinline__ float cross_comp(float a, float b, float c, float d) {
    return __fsub_rn(__fmul_rn(a, b), __fmul_rn(c, d));
}

__device__ __forceinline__ unsigned pack2(float a, float b) {
    __half2 h = __halves2half2(__float2half_rn(a), __float2half_rn(b));
    return __builtin_bit_cast(unsigned, h);
}
__device__ __forceinline__ float2 unpack2(unsigned u) {
    return __half22float2(__builtin_bit_cast(__half2, u));
}

// Stage 64 records/wave (4 KB) in LDS, then write out 1 KB contiguous per
// iteration -> every store instruction covers full lines, no RFO. Plain
// (cached) stores: these tables are re-read by the next pass, and dirty
// evictions land in L3 right where the gathers want them.
__device__ __forceinline__ void staged_record_write4(
    uint4 lds[4][64][4], const uint4 q[4], uint4* __restrict__ dstBase,
    size_t baseRec, int maxRec, int wave, int lane)
{
#pragma unroll
    for (int k = 0; k < 4; ++k)
        lds[wave][lane][(k + lane) & 3] = q[k];
    __syncthreads();
    uint4* dst = dstBase + baseRec * 4;
#pragma unroll
    for (int k = 0; k < 4; ++k) {
        int g = k * 64 + lane;          // uint4 index within wave's 4 KB
        int r = g >> 2, w = g & 3;
        if (baseRec + (size_t)r < (size_t)maxRec)
            dst[g] = lds[wave][r][(w + r) & 3];
    }
}

// ---------- CSR build (bitwise-deterministic end state) ----------

__global__ __launch_bounds__(256) void zero_count_kernel(int* __restrict__ count) {
    int i = blockIdx.x * 256 + threadIdx.x;
    if (i < kV) count[i] = 0;
}

__global__ __launch_bounds__(256) void count_kernel(
    const int* __restrict__ faces, int* __restrict__ count)
{
    int i = blockIdx.x * 256 + threadIdx.x;
    if (i >= 3 * kF) return;
    atomicAdd(&count[faces[i]], 1);
}

__device__ __forceinline__ int block_incl_scan256(int x, int* lds) {
    int lane = threadIdx.x & 63;
    int wave = threadIdx.x >> 6;
    for (int d = 1; d < 64; d <<= 1) {
        int y = __shfl_up(x, d, 64);
        if (lane >= d) x += y;
    }
    if (lane == 63) lds[wave] = x;
    __syncthreads();
    int add = 0;
    for (int w = 0; w < wave; ++w) add += lds[w];
    __syncthreads();
    return x + add;
}

__global__ __launch_bounds__(256) void scan_block_kernel(
    const int* __restrict__ count, int* __restrict__ offs,
    int* __restrict__ blockSums)
{
    __shared__ int lds[4];
    int i = blockIdx.x * 256 + threadIdx.x;
    int x = (i < kV) ? count[i] : 0;
    int incl = block_incl_scan256(x, lds);
    if (i < kV) offs[i] = incl - x;
    if (threadIdx.x == 255) blockSums[blockIdx.x] = incl;
}

__global__ __launch_bounds__(256) void scan_sums_kernel(int* __restrict__ blockSums) {
    __shared__ int lds[4];
    __shared__ int carry;
    if (threadIdx.x == 0) carry = 0;
    __syncthreads();
    for (int base = 0; base < kNB; base += 256) {
        int i = base + threadIdx.x;
        int x = (i < kNB) ? blockSums[i] : 0;
        int incl = block_incl_scan256(x, lds);
        int c = carry;
        __syncthreads();
        if (i < kNB) blockSums[i] = incl - x + c;
        if (threadIdx.x == 255) carry = c + incl;
        __syncthreads();
    }
}

__global__ __launch_bounds__(256) void add_offsets_kernel(
    int* __restrict__ offs, const int* __restrict__ blockSums)
{
    int i = blockIdx.x * 256 + threadIdx.x;
    if (i < kV) offs[i] += blockSums[i >> 8];
    if (i == kV) offs[kV] = 3 * kF;
}

// Swept fill (R10-proven): sweep s handles vertices with v>>17 == s (a
// contiguous 128K-vertex range -> ~3.1 MB adj slice + 512 KB count slice,
// L2-resident per XCD). Lines collect all their slot-writes within one
// sweep -> writeback ~12 MB instead of 3M x 64 B sectors. Separate launches
// bound each line's fill window. 4 sweeps (not 8) halves the re-scan cost.
__global__ __launch_bounds__(256) void fill_adj_sweep_kernel(
    const int* __restrict__ faces, const int* __restrict__ offs,
    int* __restrict__ count, int* __restrict__ adj, int sweep)
{
    int i = blockIdx.x * 256 + threadIdx.x;
    if (i >= 3 * kF) return;
    int v = faces[i];
    if ((v >> 17) != sweep) return;
    int f = i / 3;
    int old = atomicSub(&count[v], 1);
    adj[offs[v] + old - 1] = f;
}

// canonicalize slot order -> bitwise-deterministic adj -> deterministic fp sums
__global__ __launch_bounds__(256) void sort_rows_kernel(
    const int* __restrict__ offs, int* __restrict__ adj)
{
    int v = blockIdx.x * 256 + threadIdx.x;
    if (v >= kV) return;
    int s = offs[v], e = offs[v + 1];
    for (int i = s + 1; i < e; ++i) {
        int key = adj[i];
        int j = i - 1;
        while (j >= s && adj[j] > key) { adj[j + 1] = adj[j]; --j; }
        adj[j + 1] = key;
    }
}

// ---------- half-batch 64 B record path ----------

// verts [B][V][3] (batches half*8..+7) -> vtx8 [V][16u]; staged writes.
__global__ __launch_bounds__(256) void transpose_half16(
    const float* __restrict__ verts, unsigned* __restrict__ vtx8, int half)
{
    __shared__ uint4 lds[4][64][4];
    int tid = threadIdx.x;
    int wave = tid >> 6, lane = tid & 63;
    int v = blockIdx.x * 256 + tid;
    bool valid = v < kV;

    float o[24];
#pragma unroll
    for (int i = 0; i < 24; ++i) o[i] = 0.f;
    if (valid) {
#pragma unroll
        for (int bb = 0; bb < kHalfB; ++bb) {
            const float* p = verts + ((size_t)(half * kHalfB + bb) * kV + v) * 3;
            o[3 * bb + 0] = p[0];
            o[3 * bb + 1] = p[1];
            o[3 * bb + 2] = p[2];
        }
    }
    uint4 q[4];
#pragma unroll
    for (int k = 0; k < 3; ++k)
        q[k] = make_uint4(pack2(o[8 * k + 0], o[8 * k + 1]),
                          pack2(o[8 * k + 2], o[8 * k + 3]),
                          pack2(o[8 * k + 4], o[8 * k + 5]),
                          pack2(o[8 * k + 6], o[8 * k + 7]));
    q[3] = make_uint4(0u, 0u, 0u, 0u);

    size_t baseRec = (size_t)blockIdx.x * 256 + wave * 64;
    staged_record_write4(lds, q, reinterpret_cast<uint4*>(vtx8),
                         baseRec, kV, wave, lane);
}

// Per face: 3 ONE-sector record gathers, 8 fp32 crosses from fp16 coords,
// areas (coalesced, NT), fn8 record via staged full-line writes.
__global__ __launch_bounds__(256) void face_half16(
    const unsigned* __restrict__ vtx8, const int* __restrict__ faces,
    unsigned* __restrict__ fn8, float* __restrict__ areas, int half)
{
    __shared__ uint4 lds[4][64][4];
    int tid = threadIdx.x;
    int wave = tid >> 6, lane = tid & 63;
    int f = blockIdx.x * 256 + tid;
    bool valid = f < kF;

    float o[24];
#pragma unroll
    for (int i = 0; i < 24; ++i) o[i] = 0.f;

    if (valid) {
        int i0 = faces[3 * f + 0];
        int i1 = faces[3 * f + 1];
        int i2 = faces[3 * f + 2];
        const uint4* r0 = reinterpret_cast<const uint4*>(vtx8 + (size_t)i0 * 16);
        const uint4* r1 = reinterpret_cast<const uint4*>(vtx8 + (size_t)i1 * 16);
        const uint4* r2 = reinterpret_cast<const uint4*>(vtx8 + (size_t)i2 * 16);
        float A[24], B[24], C[24];
#pragma unroll
        for (int k = 0; k < 3; ++k) {
            uint4 ua = r0[k], ub = r1[k], uc = r2[k];
            float2 t;
            t = unpack2(ua.x); A[8 * k + 0] = t.x; A[8 * k + 1] = t.y;
            t = unpack2(ua.y); A[8 * k + 2] = t.x; A[8 * k + 3] = t.y;
            t = unpack2(ua.z); A[8 * k + 4] = t.x; A[8 * k + 5] = t.y;
            t = unpack2(ua.w); A[8 * k + 6] = t.x; A[8 * k + 7] = t.y;
            t = unpack2(ub.x); B[8 * k + 0] = t.x; B[8 * k + 1] = t.y;
            t = unpack2(ub.y); B[8 * k + 2] = t.x; B[8 * k + 3] = t.y;
            t = unpack2(ub.z); B[8 * k + 4] = t.x; B[8 * k + 5] = t.y;
            t = unpack2(ub.w); B[8 * k + 6] = t.x; B[8 * k + 7] = t.y;
            t = unpack2(uc.x); C[8 * k + 0] = t.x; C[8 * k + 1] = t.y;
            t = unpack2(uc.y); C[8 * k + 2] = t.x; C[8 * k + 3] = t.y;
            t = unpack2(uc.z); C[8 * k + 4] = t.x; C[8 * k + 5] = t.y;
            t = unpack2(uc.w); C[8 * k + 6] = t.x; C[8 * k + 7] = t.y;
        }
#pragma unroll
        for (int bb = 0; bb < kHalfB; ++bb) {
            float x0 = A[3 * bb], y0 = A[3 * bb + 1], z0 = A[3 * bb + 2];
            float x1 = B[3 * bb], y1 = B[3 * bb + 1], z1 = B[3 * bb + 2];
            float x2 = C[3 * bb], y2 = C[3 * bb + 1], z2 = C[3 * bb + 2];
            float e1x = x1 - x0, e1y = y1 - y0, e1z = z1 - z0;
            float e2x = x2 - x1, e2y = y2 - y1, e2z = z2 - z1;
            float nx = cross_comp(e1y, e2z, e1z, e2y);
            float ny = cross_comp(e1z, e2x, e1x, e2z);
            float nz = cross_comp(e1x, e2y, e1y, e2x);
            o[3 * bb + 0] = nx;
            o[3 * bb + 1] = ny;
            o[3 * bb + 2] = nz;
            __builtin_nontemporal_store(
                0.5f * sqrtf(nx * nx + ny * ny + nz * nz),
                &areas[(size_t)(half * kHalfB + bb) * kF + f]);
        }
    }

    uint4 q[4];
#pragma unroll
    for (int k = 0; k < 3; ++k)
        q[k] = make_uint4(pack2(o[8 * k + 0], o[8 * k + 1]),
                          pack2(o[8 * k + 2], o[8 * k + 3]),
                          pack2(o[8 * k + 4], o[8 * k + 5]),
                          pack2(o[8 * k + 6], o[8 * k + 7]));
    q[3] = make_uint4(0u, 0u, 0u, 0u);

    size_t baseRec = (size_t)blockIdx.x * 256 + wave * 64;
    staged_record_write4(lds, q, reinterpret_cast<uint4*>(fn8),
                         baseRec, kF, wave, lane);
}

// Per vertex: walk sorted CSR, ONE-sector fn8 gathers, fp32 accumulate,
// normalize, NT store.
__global__ __launch_bounds__(256) void vertex_half16(
    const unsigned* __restrict__ fn8, const int* __restrict__ offs,
    const int* __restrict__ adj, float* __restrict__ out, int half)
{
    int v = blockIdx.x * 256 + threadIdx.x;
    if (v >= kV) return;
    int s = offs[v], e = offs[v + 1];

    float acc[24];
#pragma unroll
    for (int i = 0; i < 24; ++i) acc[i] = 0.f;

    for (int j = s; j < e; ++j) {
        const uint4* q = reinterpret_cast<const uint4*>(fn8 + (size_t)adj[j] * 16);
        uint4 w[3];
#pragma unroll
        for (int k = 0; k < 3; ++k) w[k] = q[k];
#pragma unroll
        for (int k = 0; k < 3; ++k) {
            float2 t0 = unpack2(w[k].x), t1 = unpack2(w[k].y);
            float2 t2 = unpack2(w[k].z), t3 = unpack2(w[k].w);
            acc[8 * k + 0] += t0.x; acc[8 * k + 1] += t0.y;
            acc[8 * k + 2] += t1.x; acc[8 * k + 3] += t1.y;
            acc[8 * k + 4] += t2.x; acc[8 * k + 5] += t2.y;
            acc[8 * k + 6] += t3.x; acc[8 * k + 7] += t3.y;
        }
    }

#pragma unroll
    for (int bb = 0; bb < kHalfB; ++bb) {
        float x = acc[3 * bb], y = acc[3 * bb + 1], z = acc[3 * bb + 2];
        float n = sqrtf(x * x + y * y + z * z);
        float inv = 1.0f / fmaxf(n, kEps);
        size_t o = ((size_t)(half * kHalfB + bb) * kV + v) * 3;
        __builtin_nontemporal_store(x * inv, &out[o + 0]);
        __builtin_nontemporal_store(y * inv, &out[o + 1]);
        __builtin_nontemporal_store(z * inv, &out[o + 2]);
    }
}

// ---------- R3 fallback (ws >= 16 MB) ----------

__global__ __launch_bounds__(256) void fill_adj_kernel(
    const int* __restrict__ faces, const int* __restrict__ offs,
    int* __restrict__ count, int* __restrict__ adj)
{
    int i = blockIdx.x * 256 + threadIdx.x;
    if (i >= 3 * kF) return;
    int v = faces[i];
    int f = i / 3;
    int old = atomicSub(&count[v], 1);
    adj[offs[v] + old - 1] = f;
}

__global__ __launch_bounds__(256) void area_kernel_orig(
    const float* __restrict__ verts, const int* __restrict__ faces,
    float* __restrict__ areas)
{
    int f = blockIdx.x * 256 + threadIdx.x;
    if (f >= kF) return;
    int i0 = faces[3 * f + 0];
    int i1 = faces[3 * f + 1];
    int i2 = faces[3 * f + 2];
    size_t o0 = 3 * (size_t)i0, o1 = 3 * (size_t)i1, o2 = 3 * (size_t)i2;
#pragma unroll
    for (int b = 0; b < kB; ++b) {
        const float* vb = verts + (size_t)b * kV * 3;
        float x0 = vb[o0], y0 = vb[o0 + 1], z0 = vb[o0 + 2];
        float x1 = vb[o1], y1 = vb[o1 + 1], z1 = vb[o1 + 2];
        float x2 = vb[o2], y2 = vb[o2 + 1], z2 = vb[o2 + 2];
        float e1x = x1 - x0, e1y = y1 - y0, e1z = z1 - z0;
        float e2x = x2 - x1, e2y = y2 - y1, e2z = z2 - z1;
        float nx = cross_comp(e1y, e2z, e1z, e2y);
        float ny = cross_comp(e1z, e2x, e1x, e2z);
        float nz = cross_comp(e1x, e2y, e1y, e2x);
        areas[(size_t)b * kF + f] = 0.5f * sqrtf(nx * nx + ny * ny + nz * nz);
    }
}

__global__ __launch_bounds__(256) void gather_normalize_orig(
    const float* __restrict__ verts, const int* __restrict__ faces,
    const int* __restrict__ offs, const int* __restrict__ adj,
    float* __restrict__ out)
{
    int v = blockIdx.x * 256 + threadIdx.x;
    if (v >= kV) return;
    int s = offs[v], e = offs[v + 1];
    float ax[kB], ay[kB], az[kB];
#pragma unroll
    for (int b = 0; b < kB; ++b) { ax[b] = 0.f; ay[b] = 0.f; az[b] = 0.f; }
    for (int j = s; j < e; ++j) {
        int f = adj[j];
        int i0 = faces[3 * f + 0];
        int i1 = faces[3 * f + 1];
        int i2 = faces[3 * f + 2];
        size_t o0 = 3 * (size_t)i0, o1 = 3 * (size_t)i1, o2 = 3 * (size_t)i2;
#pragma unroll
        for (int b = 0; b < kB; ++b) {
            const float* vb = verts + (size_t)b * kV * 3;
            float x0 = vb[o0], y0 = vb[o0 + 1], z0 = vb[o0 + 2];
            float x1 = vb[o1], y1 = vb[o1 + 1], z1 = vb[o1 + 2];
            float x2 = vb[o2], y2 = vb[o2 + 1], z2 = vb[o2 + 2];
            float e1x = x1 - x0, e1y = y1 - y0, e1z = z1 - z0;
            float e2x = x2 - x1, e2y = y2 - y1, e2z = z2 - z1;
            ax[b] += cross_comp(e1y, e2z, e1z, e2y);
            ay[b] += cross_comp(e1z, e2x, e1x, e2z);
            az[b] += cross_comp(e1x, e2y, e1y, e2x);
        }
    }
#pragma unroll
    for (int b = 0; b < kB; ++b) {
        float n = sqrtf(ax[b] * ax[b] + ay[b] * ay[b] + az[b] * az[b]);
        float inv = 1.0f / fmaxf(n, kEps);
        size_t o = ((size_t)b * kV + v) * 3;
        out[o + 0] = ax[b] * inv;
        out[o + 1] = ay[b] * inv;
        out[o + 2] = az[b] * inv;
    }
}

// ---------- R1 fallback ----------

__global__ __launch_bounds__(256) void face_normals_atomic_kernel(
    const float* __restrict__ verts, const int* __restrict__ faces,
    float* __restrict__ vnorm, float* __restrict__ areas)
{
    long long tid = (long long)blockIdx.x * blockDim.x + threadIdx.x;
    if (tid >= (long long)kB * kF) return;
    int f = (int)(tid % kF);
    int b = (int)(tid / kF);
    int i0 = faces[3 * f + 0], i1 = faces[3 * f + 1], i2 = faces[3 * f + 2];
    const float* vb = verts + (size_t)b * kV * 3;
    size_t o0 = 3 * (size_t)i0, o1 = 3 * (size_t)i1, o2 = 3 * (size_t)i2;
    float x0 = vb[o0], y0 = vb[o0 + 1], z0 = vb[o0 + 2];
    float x1 = vb[o1], y1 = vb[o1 + 1], z1 = vb[o1 + 2];
    float x2 = vb[o2], y2 = vb[o2 + 1], z2 = vb[o2 + 2];
    float e1x = x1 - x0, e1y = y1 - y0, e1z = z1 - z0;
    float e2x = x2 - x1, e2y = y2 - y1, e2z = z2 - z1;
    float nx = cross_comp(e1y, e2z, e1z, e2y);
    float ny = cross_comp(e1z, e2x, e1x, e2z);
    float nz = cross_comp(e1x, e2y, e1y, e2x);
    float* vn = vnorm + (size_t)b * kV * 3;
    unsafeAtomicAdd(&vn[o0 + 0], nx); unsafeAtomicAdd(&vn[o0 + 1], ny); unsafeAtomicAdd(&vn[o0 + 2], nz);
    unsafeAtomicAdd(&vn[o1 + 0], nx); unsafeAtomicAdd(&vn[o1 + 1], ny); unsafeAtomicAdd(&vn[o1 + 2], nz);
    unsafeAtomicAdd(&vn[o2 + 0], nx); unsafeAtomicAdd(&vn[o2 + 1], ny); unsafeAtomicAdd(&vn[o2 + 2], nz);
    areas[(size_t)b * kF + f] = 0.5f * sqrtf(nx * nx + ny * ny + nz * nz);
}

__global__ __launch_bounds__(256) void normalize_inplace_kernel(float* __restrict__ vnorm) {
    long long tid = (long long)blockIdx.x * blockDim.x + threadIdx.x;
    if (tid >= (long long)kB * kV) return;
    size_t o = 3 * (size_t)tid;
    float x = vnorm[o], y = vnorm[o + 1], z = vnorm[o + 2];
    float n = sqrtf(x * x + y * y + z * z);
    float inv = 1.0f / fmaxf(n, kEps);
    vnorm[o] = x * inv; vnorm[o + 1] = y * inv; vnorm[o + 2] = z * inv;
}

// ---------- launch ----------

static void build_csr_swept(const int* faces, int* count, int* offs,
                            int* blockSums, int* adj, hipStream_t stream) {
    int gInc = (3 * kF + 255) / 256;
    zero_count_kernel<<<kNB, 256, 0, stream>>>(count);
    count_kernel<<<gInc, 256, 0, stream>>>(faces, count);
    scan_block_kernel<<<kNB, 256, 0, stream>>>(count, offs, blockSums);
    scan_sums_kernel<<<1, 256, 0, stream>>>(blockSums);
    add_offsets_kernel<<<(kV + 1 + 255) / 256, 256, 0, stream>>>(offs, blockSums);
    for (int s = 0; s < kNSweep; ++s)
        fill_adj_sweep_kernel<<<gInc, 256, 0, stream>>>(faces, offs, count, adj, s);
    sort_rows_kernel<<<kNB, 256, 0, stream>>>(offs, adj);
}

static void build_csr(const int* faces, int* count, int* offs, int* blockSums,
                      int* adj, hipStream_t stream) {
    int gInc = (3 * kF + 255) / 256;
    zero_count_kernel<<<kNB, 256, 0, stream>>>(count);
    count_kernel<<<gInc, 256, 0, stream>>>(faces, count);
    scan_block_kernel<<<kNB, 256, 0, stream>>>(count, offs, blockSums);
    scan_sums_kernel<<<1, 256, 0, stream>>>(blockSums);
    add_offsets_kernel<<<(kV + 1 + 255) / 256, 256, 0, stream>>>(offs, blockSums);
    fill_adj_kernel<<<gInc, 256, 0, stream>>>(faces, offs, count, adj);
    sort_rows_kernel<<<kNB, 256, 0, stream>>>(offs, adj);
}

extern "C" void kernel_launch(void* const* d_in, const int* in_sizes, int n_in,
                              void* d_out, int out_size, void* d_ws, size_t ws_size,
                              hipStream_t stream) {
    const float* verts = (const float*)d_in[0];
    const int*   faces = (const int*)d_in[1];

    float* out   = (float*)d_out;
    float* vecs  = out;                               // B*V*3
    float* areas = out + (size_t)kB * kV * 3;         // B*F

    int gF = (kF + 255) / 256;

    if (ws_size >= kWsHalf16) {
        unsigned* vtx8 = (unsigned*)d_ws;                     // 32 MB
        unsigned* fn8  = vtx8 + kVtx8Uints;                   // 64 MB
        int* count     = (int*)(fn8 + kFn8Uints);
        int* offs      = count + kV;
        int* blockSums = offs + (kV + 1);
        int* adj       = blockSums + kNB;

        build_csr_swept(faces, count, offs, blockSums, adj, stream);
        for (int half = 0; half < 2; ++half) {
            transpose_half16<<<kNB, 256, 0, stream>>>(verts, vtx8, half);
            face_half16<<<gF, 256, 0, stream>>>(vtx8, faces, fn8, areas, half);
            vertex_half16<<<kNB, 256, 0, stream>>>(fn8, offs, adj, vecs, half);
        }
    } else if (ws_size >= kWsC) {
        int* count     = (int*)d_ws;
        int* offs      = count + kV;
        int* blockSums = offs + (kV + 1);
        int* adj       = blockSums + kNB;

        build_csr(faces, count, offs, blockSums, adj, stream);
        area_kernel_orig<<<gF, 256, 0, stream>>>(verts, faces, areas);
        gather_normalize_orig<<<kNB, 256, 0, stream>>>(verts, faces, offs, adj, vecs);
    } else {
        (void)hipMemsetAsync(vecs, 0, (size_t)kB * kV * 3 * sizeof(float), stream);
        long long nf = (long long)kB * kF;
        face_normals_atomic_kernel<<<(int)((nf + 255) / 256), 256, 0, stream>>>(verts, faces, vecs, areas);
        long long nv = (long long)kB * kV;
        normalize_inplace_kernel<<<(int)((nv + 255) / 256), 256, 0, stream>>>(vecs);
    }
}

// Round 13
// 474.363 us; speedup vs baseline: 25.0432x; 1.4493x over previous
//
#include <hip/hip_runtime.h>
#include <hip/hip_fp16.h>
#include <math.h>

namespace {
constexpr int kB = 16;
constexpr int kV = 500000;
constexpr int kF = 1000000;
constexpr float kEps = 1e-6f;
constexpr int kNB = (kV + 255) / 256;       // 1954

// region partition for LDS-local CSR build
constexpr int kRegBits = 12;                 // 4096 vertices / region
constexpr int kRegSize = 1 << kRegBits;
constexpr int kNR   = (kV + kRegSize - 1) / kRegSize;   // 123
constexpr int kNBlkA = (3 * kF + 3071) / 3072;          // 977 (3072 items/blk)
constexpr int kBhN  = kNR * kNBlkA;                      // 120171

constexpr size_t kVtx16Uints = (size_t)kV * 32;    // 64 MB  (128 B records)
constexpr size_t kFn16Uints  = (size_t)kF * 32;    // 128 MB (128 B records)
constexpr size_t kIncPairs   = 3 * (size_t)kF;     // 24 MB (uint2)
constexpr size_t kIntWords   = (size_t)kV + (kV + 1) + kNB + 3 * (size_t)kF
                             + kBhN + (kNR + 1);
constexpr size_t kWsMain = (kVtx16Uints + kFn16Uints) * 4 + kIncPairs * 8
                         + kIntWords * 4;          // ~232.5 MB (ws >= 304 MB seen)
constexpr size_t kWsC    = ((size_t)kV + (kV + 1) + kNB + 3 * (size_t)kF) * 4;
}

// a*b - c*d unfused: degenerate faces cancel EXACTLY (matches numpy; the
// fp16-rounded coords of duplicate indices are identical, so e2 = -e1 and
// both products round identically). FMA contraction would leave ulp noise
// that normalization amplifies to O(1).
__device__ __forceinline__ float cross_comp(float a, float b, float c, float d) {
    return __fsub_rn(__fmul_rn(a, b), __fmul_rn(c, d));
}

__device__ __forceinline__ unsigned pack2(float a, float b) {
    __half2 h = __halves2half2(__float2half_rn(a), __float2half_rn(b));
    return __builtin_bit_cast(unsigned, h);
}
__device__ __forceinline__ float2 unpack2(unsigned u) {
    return __half22float2(__builtin_bit_cast(__half2, u));
}

// Stage 64 records/wave (8 KB) in LDS, then write out 1 KB contiguous per
// iteration -> every store instruction covers full 128 B lines, no RFO.
// Plain cached stores: these tables are re-read by the next pass.
__device__ __forceinline__ void staged_record_write(
    uint4 lds[4][64][8], const uint4 q[8], uint4* __restrict__ dstBase,
    size_t baseRec, int maxRec, int wave, int lane)
{
#pragma unroll
    for (int k = 0; k < 8; ++k)
        lds[wave][lane][(k + lane) & 7] = q[k];
    __syncthreads();
    uint4* dst = dstBase + baseRec * 8;
#pragma unroll
    for (int k = 0; k < 8; ++k) {
        int g = k * 64 + lane;
        int r = g >> 3, w = g & 7;
        if (baseRec + (size_t)r < (size_t)maxRec)
            dst[g] = lds[wave][r][(w + r) & 7];
    }
}

// ---------- scan helpers ----------

__device__ __forceinline__ int block_incl_scan256(int x, int* lds) {
    int lane = threadIdx.x & 63;
    int wave = threadIdx.x >> 6;
    for (int d = 1; d < 64; d <<= 1) {
        int y = __shfl_up(x, d, 64);
        if (lane >= d) x += y;
    }
    if (lane == 63) lds[wave] = x;
    __syncthreads();
    int add = 0;
    for (int w = 0; w < wave; ++w) add += lds[w];
    __syncthreads();
    return x + add;
}

__device__ __forceinline__ int block_incl_scan1024(int x, int* lds) {
    int lane = threadIdx.x & 63;
    int wave = threadIdx.x >> 6;      // 0..15
    for (int d = 1; d < 64; d <<= 1) {
        int y = __shfl_up(x, d, 64);
        if (lane >= d) x += y;
    }
    if (lane == 63) lds[wave] = x;
    __syncthreads();
    int add = 0;
    for (int w = 0; w < wave; ++w) add += lds[w];
    __syncthreads();
    return x + add;
}

// ---------- CSR build: LDS-local, no global data atomics ----------

// A1: per-block region histogram. Block handles 3072 contiguous incidences.
__global__ __launch_bounds__(256) void a1_hist_kernel(
    const int* __restrict__ faces, int* __restrict__ bh)
{
    __shared__ int h[kNR];
    int tid = threadIdx.x;
    for (int j = tid; j < kNR; j += 256) h[j] = 0;
    __syncthreads();
    size_t base = (size_t)blockIdx.x * 3072;
#pragma unroll
    for (int k = 0; k < 12; ++k) {
        size_t i = base + (size_t)k * 256 + tid;
        if (i < (size_t)3 * kF) atomicAdd(&h[faces[i] >> kRegBits], 1);
    }
    __syncthreads();
    for (int j = tid; j < kNR; j += 256)
        bh[(size_t)j * kNBlkA + blockIdx.x] = h[j];
}

// A2: single-block exclusive scan over bh (region-major) + regionBase.
__global__ __launch_bounds__(1024) void a2_scan_kernel(
    int* __restrict__ bh, int* __restrict__ regionBase)
{
    __shared__ int lds[16];
    __shared__ int carry;
    int tid = threadIdx.x;
    if (tid == 0) carry = 0;
    __syncthreads();
    for (int base = 0; base < kBhN; base += 1024) {
        int idx = base + tid;
        int x = (idx < kBhN) ? bh[idx] : 0;
        int incl = block_incl_scan1024(x, lds);
        int c = carry;
        __syncthreads();
        if (idx < kBhN) bh[idx] = incl - x + c;   // exclusive
        if (tid == 1023) carry = c + incl;
        __syncthreads();
    }
    if (tid < kNR) regionBase[tid] = bh[(size_t)tid * kNBlkA];
    if (tid == 0) regionBase[kNR] = 3 * kF;
}

// A3: scatter (v,f) pairs region-major using precomputed per-(blk,region)
// cursors + LDS-local slots. No global atomics; window content per
// (block,region) is a deterministic set.
__global__ __launch_bounds__(256) void a3_scatter_kernel(
    const int* __restrict__ faces, const int* __restrict__ bh,
    uint2* __restrict__ inc)
{
    __shared__ int cur[kNR];
    int tid = threadIdx.x;
    for (int j = tid; j < kNR; j += 256)
        cur[j] = bh[(size_t)j * kNBlkA + blockIdx.x];
    __syncthreads();
    size_t base = (size_t)blockIdx.x * 3072;
#pragma unroll
    for (int k = 0; k < 12; ++k) {
        size_t i = base + (size_t)k * 256 + tid;
        if (i < (size_t)3 * kF) {
            int v = faces[i];
            int f = (int)(i / 3);
            int pos = atomicAdd(&cur[v >> kRegBits], 1);
            inc[pos] = make_uint2((unsigned)v, (unsigned)f);
        }
    }
}

// K1: one block per region; LDS histogram (16 KB); coalesced count write.
__global__ __launch_bounds__(1024) void k1_count_kernel(
    const uint2* __restrict__ inc, const int* __restrict__ regionBase,
    int* __restrict__ count)
{
    __shared__ int h[kRegSize];
    int tid = threadIdx.x;
    int r = blockIdx.x;
    for (int j = tid; j < kRegSize; j += 1024) h[j] = 0;
    __syncthreads();
    int s = regionBase[r], e = regionBase[r + 1];
    for (int j = s + tid; j < e; j += 1024)
        atomicAdd(&h[inc[j].x & (kRegSize - 1)], 1);
    __syncthreads();
    int vbase = r << kRegBits;
    for (int j = tid; j < kRegSize; j += 1024) {
        int v = vbase + j;
        if (v < kV) count[v] = h[j];
    }
}

__global__ __launch_bounds__(256) void scan_block_kernel(
    const int* __restrict__ count, int* __restrict__ offs,
    int* __restrict__ blockSums)
{
    __shared__ int lds[4];
    int i = blockIdx.x * 256 + threadIdx.x;
    int x = (i < kV) ? count[i] : 0;
    int incl = block_incl_scan256(x, lds);
    if (i < kV) offs[i] = incl - x;
    if (threadIdx.x == 255) blockSums[blockIdx.x] = incl;
}

__global__ __launch_bounds__(256) void scan_sums_kernel(int* __restrict__ blockSums) {
    __shared__ int lds[4];
    __shared__ int carry;
    if (threadIdx.x == 0) carry = 0;
    __syncthreads();
    for (int base = 0; base < kNB; base += 256) {
        int i = base + threadIdx.x;
        int x = (i < kNB) ? blockSums[i] : 0;
        int incl = block_incl_scan256(x, lds);
        int c = carry;
        __syncthreads();
        if (i < kNB) blockSums[i] = incl - x + c;
        if (threadIdx.x == 255) carry = c + incl;
        __syncthreads();
    }
}

__global__ __launch_bounds__(256) void add_offsets_kernel(
    int* __restrict__ offs, const int* __restrict__ blockSums)
{
    int i = blockIdx.x * 256 + threadIdx.x;
    if (i < kV) offs[i] += blockSums[i >> 8];
    if (i == kV) offs[kV] = 3 * kF;
}

// K3: one block per region; LDS cursors; adj writes land in an L2-resident
// ~190 KB slice. Only LDS atomics (content-deterministic multiset per v).
__global__ __launch_bounds__(1024) void k3_fill_kernel(
    const uint2* __restrict__ inc, const int* __restrict__ regionBase,
    const int* __restrict__ offs, int* __restrict__ adj)
{
    __shared__ int cur[kRegSize];
    int tid = threadIdx.x;
    int r = blockIdx.x;
    for (int j = tid; j < kRegSize; j += 1024) cur[j] = 0;
    __syncthreads();
    int s = regionBase[r], e = regionBase[r + 1];
    for (int j = s + tid; j < e; j += 1024) {
        uint2 p = inc[j];
        int v = (int)p.x;
        int slot = atomicAdd(&cur[v & (kRegSize - 1)], 1);
        adj[offs[v] + slot] = (int)p.y;
    }
}

// canonicalize slot order -> bitwise-deterministic adj -> deterministic fp sums
__global__ __launch_bounds__(256) void sort_rows_kernel(
    const int* __restrict__ offs, int* __restrict__ adj)
{
    int v = blockIdx.x * 256 + threadIdx.x;
    if (v >= kV) return;
    int s = offs[v], e = offs[v + 1];
    for (int i = s + 1; i < e; ++i) {
        int key = adj[i];
        int j = i - 1;
        while (j >= s && adj[j] > key) { adj[j + 1] = adj[j]; --j; }
        adj[j + 1] = key;
    }
}

// ---------- fp16 128 B record pipeline (R9-proven) ----------

__global__ __launch_bounds__(256) void transpose_kernel16(
    const float* __restrict__ verts, unsigned* __restrict__ vtx16)
{
    __shared__ uint4 lds[4][64][8];
    int tid = threadIdx.x;
    int wave = tid >> 6, lane = tid & 63;
    int v = blockIdx.x * 256 + tid;
    bool valid = v < kV;

    float o[48];
#pragma unroll
    for (int i = 0; i < 48; ++i) o[i] = 0.f;
    if (valid) {
#pragma unroll
        for (int b = 0; b < kB; ++b) {
            const float* p = verts + ((size_t)b * kV + v) * 3;
            o[3 * b + 0] = p[0];
            o[3 * b + 1] = p[1];
            o[3 * b + 2] = p[2];
        }
    }
    uint4 q[8];
#pragma unroll
    for (int k = 0; k < 6; ++k)
        q[k] = make_uint4(pack2(o[8 * k + 0], o[8 * k + 1]),
                          pack2(o[8 * k + 2], o[8 * k + 3]),
                          pack2(o[8 * k + 4], o[8 * k + 5]),
                          pack2(o[8 * k + 6], o[8 * k + 7]));
    q[6] = make_uint4(0u, 0u, 0u, 0u);
    q[7] = make_uint4(0u, 0u, 0u, 0u);

    size_t baseRec = (size_t)blockIdx.x * 256 + wave * 64;
    staged_record_write(lds, q, reinterpret_cast<uint4*>(vtx16),
                        baseRec, kV, wave, lane);
}

__global__ __launch_bounds__(256) void face_kernel16(
    const unsigned* __restrict__ vtx16, const int* __restrict__ faces,
    unsigned* __restrict__ fn16, float* __restrict__ areas)
{
    __shared__ uint4 lds[4][64][8];
    int tid = threadIdx.x;
    int wave = tid >> 6, lane = tid & 63;
    int f = blockIdx.x * 256 + tid;
    bool valid = f < kF;

    float o[48];
#pragma unroll
    for (int i = 0; i < 48; ++i) o[i] = 0.f;

    if (valid) {
        int i0 = faces[3 * f + 0];
        int i1 = faces[3 * f + 1];
        int i2 = faces[3 * f + 2];
        const uint4* r0 = reinterpret_cast<const uint4*>(vtx16 + (size_t)i0 * 32);
        const uint4* r1 = reinterpret_cast<const uint4*>(vtx16 + (size_t)i1 * 32);
        const uint4* r2 = reinterpret_cast<const uint4*>(vtx16 + (size_t)i2 * 32);
#pragma unroll
        for (int g = 0; g < 2; ++g) {
            float A[24], B[24], C[24];
#pragma unroll
            for (int k = 0; k < 3; ++k) {
                uint4 ua = r0[3 * g + k], ub = r1[3 * g + k], uc = r2[3 * g + k];
                float2 t;
                t = unpack2(ua.x); A[8 * k + 0] = t.x; A[8 * k + 1] = t.y;
                t = unpack2(ua.y); A[8 * k + 2] = t.x; A[8 * k + 3] = t.y;
                t = unpack2(ua.z); A[8 * k + 4] = t.x; A[8 * k + 5] = t.y;
                t = unpack2(ua.w); A[8 * k + 6] = t.x; A[8 * k + 7] = t.y;
                t = unpack2(ub.x); B[8 * k + 0] = t.x; B[8 * k + 1] = t.y;
                t = unpack2(ub.y); B[8 * k + 2] = t.x; B[8 * k + 3] = t.y;
                t = unpack2(ub.z); B[8 * k + 4] = t.x; B[8 * k + 5] = t.y;
                t = unpack2(ub.w); B[8 * k + 6] = t.x; B[8 * k + 7] = t.y;
                t = unpack2(uc.x); C[8 * k + 0] = t.x; C[8 * k + 1] = t.y;
                t = unpack2(uc.y); C[8 * k + 2] = t.x; C[8 * k + 3] = t.y;
                t = unpack2(uc.z); C[8 * k + 4] = t.x; C[8 * k + 5] = t.y;
                t = unpack2(uc.w); C[8 * k + 6] = t.x; C[8 * k + 7] = t.y;
            }
#pragma unroll
            for (int bb = 0; bb < 8; ++bb) {
                float x0 = A[3 * bb], y0 = A[3 * bb + 1], z0 = A[3 * bb + 2];
                float x1 = B[3 * bb], y1 = B[3 * bb + 1], z1 = B[3 * bb + 2];
                float x2 = C[3 * bb], y2 = C[3 * bb + 1], z2 = C[3 * bb + 2];
                float e1x = x1 - x0, e1y = y1 - y0, e1z = z1 - z0;
                float e2x = x2 - x1, e2y = y2 - y1, e2z = z2 - z1;
                float nx = cross_comp(e1y, e2z, e1z, e2y);
                float ny = cross_comp(e1z, e2x, e1x, e2z);
                float nz = cross_comp(e1x, e2y, e1y, e2x);
                int bi = 8 * g + bb;
                o[3 * bi + 0] = nx;
                o[3 * bi + 1] = ny;
                o[3 * bi + 2] = nz;
                __builtin_nontemporal_store(
                    0.5f * sqrtf(nx * nx + ny * ny + nz * nz),
                    &areas[(size_t)bi * kF + f]);
            }
        }
    }

    uint4 q[8];
#pragma unroll
    for (int k = 0; k < 6; ++k)
        q[k] = make_uint4(pack2(o[8 * k + 0], o[8 * k + 1]),
                          pack2(o[8 * k + 2], o[8 * k + 3]),
                          pack2(o[8 * k + 4], o[8 * k + 5]),
                          pack2(o[8 * k + 6], o[8 * k + 7]));
    q[6] = make_uint4(0u, 0u, 0u, 0u);
    q[7] = make_uint4(0u, 0u, 0u, 0u);

    size_t baseRec = (size_t)blockIdx.x * 256 + wave * 64;
    staged_record_write(lds, q, reinterpret_cast<uint4*>(fn16),
                        baseRec, kF, wave, lane);
}

__global__ __launch_bounds__(256) void vertex_kernel16(
    const unsigned* __restrict__ fn16, const int* __restrict__ offs,
    const int* __restrict__ adj, float* __restrict__ out)
{
    int v = blockIdx.x * 256 + threadIdx.x;
    if (v >= kV) return;
    int s = offs[v], e = offs[v + 1];

    float acc[48];
#pragma unroll
    for (int i = 0; i < 48; ++i) acc[i] = 0.f;

    for (int j = s; j < e; ++j) {
        const uint4* q = reinterpret_cast<const uint4*>(fn16 + (size_t)adj[j] * 32);
        uint4 w[6];
#pragma unroll
        for (int k = 0; k < 6; ++k) w[k] = q[k];
#pragma unroll
        for (int k = 0; k < 6; ++k) {
            float2 t0 = unpack2(w[k].x), t1 = unpack2(w[k].y);
            float2 t2 = unpack2(w[k].z), t3 = unpack2(w[k].w);
            acc[8 * k + 0] += t0.x; acc[8 * k + 1] += t0.y;
            acc[8 * k + 2] += t1.x; acc[8 * k + 3] += t1.y;
            acc[8 * k + 4] += t2.x; acc[8 * k + 5] += t2.y;
            acc[8 * k + 6] += t3.x; acc[8 * k + 7] += t3.y;
        }
    }

#pragma unroll
    for (int bi = 0; bi < kB; ++bi) {
        float x = acc[3 * bi], y = acc[3 * bi + 1], z = acc[3 * bi + 2];
        float n = sqrtf(x * x + y * y + z * z);
        float inv = 1.0f / fmaxf(n, kEps);
        size_t o = ((size_t)bi * kV + v) * 3;
        __builtin_nontemporal_store(x * inv, &out[o + 0]);
        __builtin_nontemporal_store(y * inv, &out[o + 1]);
        __builtin_nontemporal_store(z * inv, &out[o + 2]);
    }
}

// ---------- R3 fallback (ws >= 16 MB) ----------

__global__ __launch_bounds__(256) void zero_count_kernel(int* __restrict__ count) {
    int i = blockIdx.x * 256 + threadIdx.x;
    if (i < kV) count[i] = 0;
}

__global__ __launch_bounds__(256) void count_kernel(
    const int* __restrict__ faces, int* __restrict__ count)
{
    int i = blockIdx.x * 256 + threadIdx.x;
    if (i >= 3 * kF) return;
    atomicAdd(&count[faces[i]], 1);
}

__global__ __launch_bounds__(256) void fill_adj_kernel(
    const int* __restrict__ faces, const int* __restrict__ offs,
    int* __restrict__ count, int* __restrict__ adj)
{
    int i = blockIdx.x * 256 + threadIdx.x;
    if (i >= 3 * kF) return;
    int v = faces[i];
    int f = i / 3;
    int old = atomicSub(&count[v], 1);
    adj[offs[v] + old - 1] = f;
}

__global__ __launch_bounds__(256) void area_kernel_orig(
    const float* __restrict__ verts, const int* __restrict__ faces,
    float* __restrict__ areas)
{
    int f = blockIdx.x * 256 + threadIdx.x;
    if (f >= kF) return;
    int i0 = faces[3 * f + 0];
    int i1 = faces[3 * f + 1];
    int i2 = faces[3 * f + 2];
    size_t o0 = 3 * (size_t)i0, o1 = 3 * (size_t)i1, o2 = 3 * (size_t)i2;
#pragma unroll
    for (int b = 0; b < kB; ++b) {
        const float* vb = verts + (size_t)b * kV * 3;
        float x0 = vb[o0], y0 = vb[o0 + 1], z0 = vb[o0 + 2];
        float x1 = vb[o1], y1 = vb[o1 + 1], z1 = vb[o1 + 2];
        float x2 = vb[o2], y2 = vb[o2 + 1], z2 = vb[o2 + 2];
        float e1x = x1 - x0, e1y = y1 - y0, e1z = z1 - z0;
        float e2x = x2 - x1, e2y = y2 - y1, e2z = z2 - z1;
        float nx = cross_comp(e1y, e2z, e1z, e2y);
        float ny = cross_comp(e1z, e2x, e1x, e2z);
        float nz = cross_comp(e1x, e2y, e1y, e2x);
        areas[(size_t)b * kF + f] = 0.5f * sqrtf(nx * nx + ny * ny + nz * nz);
    }
}

__global__ __launch_bounds__(256) void gather_normalize_orig(
    const float* __restrict__ verts, const int* __restrict__ faces,
    const int* __restrict__ offs, const int* __restrict__ adj,
    float* __restrict__ out)
{
    int v = blockIdx.x * 256 + threadIdx.x;
    if (v >= kV) return;
    int s = offs[v], e = offs[v + 1];
    float ax[kB], ay[kB], az[kB];
#pragma unroll
    for (int b = 0; b < kB; ++b) { ax[b] = 0.f; ay[b] = 0.f; az[b] = 0.f; }
    for (int j = s; j < e; ++j) {
        int f = adj[j];
        int i0 = faces[3 * f + 0];
        int i1 = faces[3 * f + 1];
        int i2 = faces[3 * f + 2];
        size_t o0 = 3 * (size_t)i0, o1 = 3 * (size_t)i1, o2 = 3 * (size_t)i2;
#pragma unroll
        for (int b = 0; b < kB; ++b) {
            const float* vb = verts + (size_t)b * kV * 3;
            float x0 = vb[o0], y0 = vb[o0 + 1], z0 = vb[o0 + 2];
            float x1 = vb[o1], y1 = vb[o1 + 1], z1 = vb[o1 + 2];
            float x2 = vb[o2], y2 = vb[o2 + 1], z2 = vb[o2 + 2];
            float e1x = x1 - x0, e1y = y1 - y0, e1z = z1 - z0;
            float e2x = x2 - x1, e2y = y2 - y1, e2z = z2 - z1;
            ax[b] += cross_comp(e1y, e2z, e1z, e2y);
            ay[b] += cross_comp(e1z, e2x, e1x, e2z);
            az[b] += cross_comp(e1x, e2y, e1y, e2x);
        }
    }
#pragma unroll
    for (int b = 0; b < kB; ++b) {
        float n = sqrtf(ax[b] * ax[b] + ay[b] * ay[b] + az[b] * az[b]);
        float inv = 1.0f / fmaxf(n, kEps);
        size_t o = ((size_t)b * kV + v) * 3;
        out[o + 0] = ax[b] * inv;
        out[o + 1] = ay[b] * inv;
        out[o + 2] = az[b] * inv;
    }
}

// ---------- R1 fallback ----------

__global__ __launch_bounds__(256) void face_normals_atomic_kernel(
    const float* __restrict__ verts, const int* __restrict__ faces,
    float* __restrict__ vnorm, float* __restrict__ areas)
{
    long long tid = (long long)blockIdx.x * blockDim.x + threadIdx.x;
    if (tid >= (long long)kB * kF) return;
    int f = (int)(tid % kF);
    int b = (int)(tid / kF);
    int i0 = faces[3 * f + 0], i1 = faces[3 * f + 1], i2 = faces[3 * f + 2];
    const float* vb = verts + (size_t)b * kV * 3;
    size_t o0 = 3 * (size_t)i0, o1 = 3 * (size_t)i1, o2 = 3 * (size_t)i2;
    float x0 = vb[o0], y0 = vb[o0 + 1], z0 = vb[o0 + 2];
    float x1 = vb[o1], y1 = vb[o1 + 1], z1 = vb[o1 + 2];
    float x2 = vb[o2], y2 = vb[o2 + 1], z2 = vb[o2 + 2];
    float e1x = x1 - x0, e1y = y1 - y0, e1z = z1 - z0;
    float e2x = x2 - x1, e2y = y2 - y1, e2z = z2 - z1;
    float nx = cross_comp(e1y, e2z, e1z, e2y);
    float ny = cross_comp(e1z, e2x, e1x, e2z);
    float nz = cross_comp(e1x, e2y, e1y, e2x);
    float* vn = vnorm + (size_t)b * kV * 3;
    unsafeAtomicAdd(&vn[o0 + 0], nx); unsafeAtomicAdd(&vn[o0 + 1], ny); unsafeAtomicAdd(&vn[o0 + 2], nz);
    unsafeAtomicAdd(&vn[o1 + 0], nx); unsafeAtomicAdd(&vn[o1 + 1], ny); unsafeAtomicAdd(&vn[o1 + 2], nz);
    unsafeAtomicAdd(&vn[o2 + 0], nx); unsafeAtomicAdd(&vn[o2 + 1], ny); unsafeAtomicAdd(&vn[o2 + 2], nz);
    areas[(size_t)b * kF + f] = 0.5f * sqrtf(nx * nx + ny * ny + nz * nz);
}

__global__ __launch_bounds__(256) void normalize_inplace_kernel(float* __restrict__ vnorm) {
    long long tid = (long long)blockIdx.x * blockDim.x + threadIdx.x;
    if (tid >= (long long)kB * kV) return;
    size_t o = 3 * (size_t)tid;
    float x = vnorm[o], y = vnorm[o + 1], z = vnorm[o + 2];
    float n = sqrtf(x * x + y * y + z * z);
    float inv = 1.0f / fmaxf(n, kEps);
    vnorm[o] = x * inv; vnorm[o + 1] = y * inv; vnorm[o + 2] = z * inv;
}

// ---------- launch ----------

static void build_csr(const int* faces, int* count, int* offs, int* blockSums,
                      int* adj, hipStream_t stream) {
    int gInc = (3 * kF + 255) / 256;
    zero_count_kernel<<<kNB, 256, 0, stream>>>(count);
    count_kernel<<<gInc, 256, 0, stream>>>(faces, count);
    scan_block_kernel<<<kNB, 256, 0, stream>>>(count, offs, blockSums);
    scan_sums_kernel<<<1, 256, 0, stream>>>(blockSums);
    add_offsets_kernel<<<(kV + 1 + 255) / 256, 256, 0, stream>>>(offs, blockSums);
    fill_adj_kernel<<<gInc, 256, 0, stream>>>(faces, offs, count, adj);
    sort_rows_kernel<<<kNB, 256, 0, stream>>>(offs, adj);
}

extern "C" void kernel_launch(void* const* d_in, const int* in_sizes, int n_in,
                              void* d_out, int out_size, void* d_ws, size_t ws_size,
                              hipStream_t stream) {
    const float* verts = (const float*)d_in[0];
    const int*   faces = (const int*)d_in[1];

    float* out   = (float*)d_out;
    float* vecs  = out;                               // B*V*3
    float* areas = out + (size_t)kB * kV * 3;         // B*F

    int gF = (kF + 255) / 256;

    if (ws_size >= kWsMain) {
        unsigned* vtx16 = (unsigned*)d_ws;                    // 64 MB
        unsigned* fn16  = vtx16 + kVtx16Uints;                // 128 MB
        uint2*    inc   = (uint2*)(fn16 + kFn16Uints);        // 24 MB
        int* count      = (int*)(inc + kIncPairs);
        int* offs       = count + kV;
        int* blockSums  = offs + (kV + 1);
        int* adj        = blockSums + kNB;
        int* bh         = adj + 3 * (size_t)kF;               // kBhN
        int* regionBase = bh + kBhN;                          // kNR+1

        a1_hist_kernel<<<kNBlkA, 256, 0, stream>>>(faces, bh);
        a2_scan_kernel<<<1, 1024, 0, stream>>>(bh, regionBase);
        a3_scatter_kernel<<<kNBlkA, 256, 0, stream>>>(faces, bh, inc);
        k1_count_kernel<<<kNR, 1024, 0, stream>>>(inc, regionBase, count);
        scan_block_kernel<<<kNB, 256, 0, stream>>>(count, offs, blockSums);
        scan_sums_kernel<<<1, 256, 0, stream>>>(blockSums);
        add_offsets_kernel<<<(kV + 1 + 255) / 256, 256, 0, stream>>>(offs, blockSums);
        k3_fill_kernel<<<kNR, 1024, 0, stream>>>(inc, regionBase, offs, adj);
        sort_rows_kernel<<<kNB, 256, 0, stream>>>(offs, adj);

        transpose_kernel16<<<kNB, 256, 0, stream>>>(verts, vtx16);
        face_kernel16<<<gF, 256, 0, stream>>>(vtx16, faces, fn16, areas);
        vertex_kernel16<<<kNB, 256, 0, stream>>>(fn16, offs, adj, vecs);
    } else if (ws_size >= kWsC) {
        int* count     = (int*)d_ws;
        int* offs      = count + kV;
        int* blockSums = offs + (kV + 1);
        int* adj       = blockSums + kNB;

        build_csr(faces, count, offs, blockSums, adj, stream);
        area_kernel_orig<<<gF, 256, 0, stream>>>(verts, faces, areas);
        gather_normalize_orig<<<kNB, 256, 0, stream>>>(verts, faces, offs, adj, vecs);
    } else {
        (void)hipMemsetAsync(vecs, 0, (size_t)kB * kV * 3 * sizeof(float), stream);
        long long nf = (long long)kB * kF;
        face_normals_atomic_kernel<<<(int)((nf + 255) / 256), 256, 0, stream>>>(verts, faces, vecs, areas);
        long long nv = (long long)kB * kV;
        normalize_inplace_kernel<<<(int)((nv + 255) / 256), 256, 0, stream>>>(vecs);
    }
}

// Round 14
// 343.254 us; speedup vs baseline: 34.6086x; 1.3820x over previous
//
#include <hip/hip_runtime.h>
#include <hip/hip_fp16.h>
#include <math.h>

namespace {
constexpr int kB = 16;
constexpr int kV = 500000;
constexpr int kF = 1000000;
constexpr float kEps = 1e-6f;
constexpr int kNB = (kV + 255) / 256;       // 1954

// region partition for LDS-local CSR build
constexpr int kRegBits = 12;                 // 4096 vertices / region
constexpr int kRegSize = 1 << kRegBits;
constexpr int kNR   = (kV + kRegSize - 1) / kRegSize;   // 123
constexpr int kNBlkA = (3 * kF + 3071) / 3072;          // 977 (3072 items/blk)
constexpr int kBhN  = kNR * kNBlkA;                      // 120171

constexpr size_t kVtx16Uints = (size_t)kV * 32;    // 64 MB  (128 B records)
constexpr size_t kFn16Uints  = (size_t)kF * 32;    // 128 MB (128 B records)
constexpr size_t kIncPairs   = 3 * (size_t)kF;     // 24 MB (uint2)
constexpr size_t kIntWords   = (size_t)kV + (kV + 1) + kNB + 3 * (size_t)kF
                             + kBhN + (kNR + 1) + kNR;
constexpr size_t kWsMain = (kVtx16Uints + kFn16Uints) * 4 + kIncPairs * 8
                         + kIntWords * 4;          // ~232.5 MB
constexpr size_t kWsC    = ((size_t)kV + (kV + 1) + kNB + 3 * (size_t)kF) * 4;
}

// a*b - c*d unfused: degenerate faces cancel EXACTLY (matches numpy; the
// fp16-rounded coords of duplicate indices are identical, so e2 = -e1 and
// both products round identically). FMA contraction would leave ulp noise
// that normalization amplifies to O(1).
__device__ __forceinline__ float cross_comp(float a, float b, float c, float d) {
    return __fsub_rn(__fmul_rn(a, b), __fmul_rn(c, d));
}

__device__ __forceinline__ unsigned pack2(float a, float b) {
    __half2 h = __halves2half2(__float2half_rn(a), __float2half_rn(b));
    return __builtin_bit_cast(unsigned, h);
}
__device__ __forceinline__ float2 unpack2(unsigned u) {
    return __half22float2(__builtin_bit_cast(__half2, u));
}

// Stage 64 records/wave (8 KB) in LDS, then write out 1 KB contiguous per
// iteration -> every store instruction covers full 128 B lines, no RFO.
__device__ __forceinline__ void staged_record_write(
    uint4 lds[4][64][8], const uint4 q[8], uint4* __restrict__ dstBase,
    size_t baseRec, int maxRec, int wave, int lane)
{
#pragma unroll
    for (int k = 0; k < 8; ++k)
        lds[wave][lane][(k + lane) & 7] = q[k];
    __syncthreads();
    uint4* dst = dstBase + baseRec * 8;
#pragma unroll
    for (int k = 0; k < 8; ++k) {
        int g = k * 64 + lane;
        int r = g >> 3, w = g & 7;
        if (baseRec + (size_t)r < (size_t)maxRec)
            dst[g] = lds[wave][r][(w + r) & 7];
    }
}

// ---------- scan helper ----------

__device__ __forceinline__ int block_incl_scan256(int x, int* lds) {
    int lane = threadIdx.x & 63;
    int wave = threadIdx.x >> 6;
    for (int d = 1; d < 64; d <<= 1) {
        int y = __shfl_up(x, d, 64);
        if (lane >= d) x += y;
    }
    if (lane == 63) lds[wave] = x;
    __syncthreads();
    int add = 0;
    for (int w = 0; w < wave; ++w) add += lds[w];
    __syncthreads();
    return x + add;
}

// ---------- CSR build: LDS-local, no global data atomics ----------

// A1: per-block region histogram. Block handles 3072 contiguous incidences.
__global__ __launch_bounds__(256) void a1_hist_kernel(
    const int* __restrict__ faces, int* __restrict__ bh)
{
    __shared__ int h[kNR];
    int tid = threadIdx.x;
    for (int j = tid; j < kNR; j += 256) h[j] = 0;
    __syncthreads();
    size_t base = (size_t)blockIdx.x * 3072;
#pragma unroll
    for (int k = 0; k < 12; ++k) {
        size_t i = base + (size_t)k * 256 + tid;
        if (i < (size_t)3 * kF) atomicAdd(&h[faces[i] >> kRegBits], 1);
    }
    __syncthreads();
    for (int j = tid; j < kNR; j += 256)
        bh[(size_t)j * kNBlkA + blockIdx.x] = h[j];
}

// S1: per-region EXCLUSIVE scan of bh row (977 entries) — 123 parallel
// blocks replace the old single-block 120K-entry scan (was 141 us, pure
// serialization on one CU). Emits region total.
__global__ __launch_bounds__(256) void s1_region_scan_kernel(
    int* __restrict__ bh, int* __restrict__ regionSum)
{
    __shared__ int lds[4];
    __shared__ int carry;
    int r = blockIdx.x;
    int tid = threadIdx.x;
    if (tid == 0) carry = 0;
    __syncthreads();
    size_t base = (size_t)r * kNBlkA;
    for (int off = 0; off < kNBlkA; off += 256) {
        int idx = off + tid;
        int x = (idx < kNBlkA) ? bh[base + idx] : 0;
        int incl = block_incl_scan256(x, lds);
        int c = carry;
        __syncthreads();
        if (idx < kNBlkA) bh[base + idx] = incl - x + c;   // exclusive-in-region
        if (tid == 255) carry = c + incl;
        __syncthreads();
    }
    if (tid == 0) regionSum[r] = carry;
}

// S2: tiny scan of 123 region totals -> regionBase (exclusive).
__global__ __launch_bounds__(256) void s2_base_scan_kernel(
    const int* __restrict__ regionSum, int* __restrict__ regionBase)
{
    __shared__ int lds[4];
    int tid = threadIdx.x;
    int x = (tid < kNR) ? regionSum[tid] : 0;
    int incl = block_incl_scan256(x, lds);
    if (tid < kNR) regionBase[tid] = incl - x;
    if (tid == 0) regionBase[kNR] = 3 * kF;
}

// A3: scatter (v,f) pairs region-major using per-(blk,region) cursors
// (bh + regionBase folded in) + LDS slots. No global atomics.
__global__ __launch_bounds__(256) void a3_scatter_kernel(
    const int* __restrict__ faces, const int* __restrict__ bh,
    const int* __restrict__ regionBase, uint2* __restrict__ inc)
{
    __shared__ int cur[kNR];
    int tid = threadIdx.x;
    for (int j = tid; j < kNR; j += 256)
        cur[j] = bh[(size_t)j * kNBlkA + blockIdx.x] + regionBase[j];
    __syncthreads();
    size_t base = (size_t)blockIdx.x * 3072;
#pragma unroll
    for (int k = 0; k < 12; ++k) {
        size_t i = base + (size_t)k * 256 + tid;
        if (i < (size_t)3 * kF) {
            int v = faces[i];
            int f = (int)(i / 3);
            int pos = atomicAdd(&cur[v >> kRegBits], 1);
            inc[pos] = make_uint2((unsigned)v, (unsigned)f);
        }
    }
}

// K1: one block per region; LDS histogram (16 KB); coalesced count write.
__global__ __launch_bounds__(1024) void k1_count_kernel(
    const uint2* __restrict__ inc, const int* __restrict__ regionBase,
    int* __restrict__ count)
{
    __shared__ int h[kRegSize];
    int tid = threadIdx.x;
    int r = blockIdx.x;
    for (int j = tid; j < kRegSize; j += 1024) h[j] = 0;
    __syncthreads();
    int s = regionBase[r], e = regionBase[r + 1];
    for (int j = s + tid; j < e; j += 1024)
        atomicAdd(&h[inc[j].x & (kRegSize - 1)], 1);
    __syncthreads();
    int vbase = r << kRegBits;
    for (int j = tid; j < kRegSize; j += 1024) {
        int v = vbase + j;
        if (v < kV) count[v] = h[j];
    }
}

__global__ __launch_bounds__(256) void scan_block_kernel(
    const int* __restrict__ count, int* __restrict__ offs,
    int* __restrict__ blockSums)
{
    __shared__ int lds[4];
    int i = blockIdx.x * 256 + threadIdx.x;
    int x = (i < kV) ? count[i] : 0;
    int incl = block_incl_scan256(x, lds);
    if (i < kV) offs[i] = incl - x;
    if (threadIdx.x == 255) blockSums[blockIdx.x] = incl;
}

__global__ __launch_bounds__(256) void scan_sums_kernel(int* __restrict__ blockSums) {
    __shared__ int lds[4];
    __shared__ int carry;
    if (threadIdx.x == 0) carry = 0;
    __syncthreads();
    for (int base = 0; base < kNB; base += 256) {
        int i = base + threadIdx.x;
        int x = (i < kNB) ? blockSums[i] : 0;
        int incl = block_incl_scan256(x, lds);
        int c = carry;
        __syncthreads();
        if (i < kNB) blockSums[i] = incl - x + c;
        if (threadIdx.x == 255) carry = c + incl;
        __syncthreads();
    }
}

__global__ __launch_bounds__(256) void add_offsets_kernel(
    int* __restrict__ offs, const int* __restrict__ blockSums)
{
    int i = blockIdx.x * 256 + threadIdx.x;
    if (i < kV) offs[i] += blockSums[i >> 8];
    if (i == kV) offs[kV] = 3 * kF;
}

// K3: one block per region; LDS cursors; adj writes in an L2-resident slice.
__global__ __launch_bounds__(1024) void k3_fill_kernel(
    const uint2* __restrict__ inc, const int* __restrict__ regionBase,
    const int* __restrict__ offs, int* __restrict__ adj)
{
    __shared__ int cur[kRegSize];
    int tid = threadIdx.x;
    int r = blockIdx.x;
    for (int j = tid; j < kRegSize; j += 1024) cur[j] = 0;
    __syncthreads();
    int s = regionBase[r], e = regionBase[r + 1];
    for (int j = s + tid; j < e; j += 1024) {
        uint2 p = inc[j];
        int v = (int)p.x;
        int slot = atomicAdd(&cur[v & (kRegSize - 1)], 1);
        adj[offs[v] + slot] = (int)p.y;
    }
}

// canonicalize slot order -> bitwise-deterministic adj -> deterministic fp sums
__global__ __launch_bounds__(256) void sort_rows_kernel(
    const int* __restrict__ offs, int* __restrict__ adj)
{
    int v = blockIdx.x * 256 + threadIdx.x;
    if (v >= kV) return;
    int s = offs[v], e = offs[v + 1];
    for (int i = s + 1; i < e; ++i) {
        int key = adj[i];
        int j = i - 1;
        while (j >= s && adj[j] > key) { adj[j + 1] = adj[j]; --j; }
        adj[j + 1] = key;
    }
}

// ---------- fp16 128 B record pipeline ----------

__global__ __launch_bounds__(256) void transpose_kernel16(
    const float* __restrict__ verts, unsigned* __restrict__ vtx16)
{
    __shared__ uint4 lds[4][64][8];
    int tid = threadIdx.x;
    int wave = tid >> 6, lane = tid & 63;
    int v = blockIdx.x * 256 + tid;
    bool valid = v < kV;

    float o[48];
#pragma unroll
    for (int i = 0; i < 48; ++i) o[i] = 0.f;
    if (valid) {
#pragma unroll
        for (int b = 0; b < kB; ++b) {
            const float* p = verts + ((size_t)b * kV + v) * 3;
            o[3 * b + 0] = p[0];
            o[3 * b + 1] = p[1];
            o[3 * b + 2] = p[2];
        }
    }
    uint4 q[8];
#pragma unroll
    for (int k = 0; k < 6; ++k)
        q[k] = make_uint4(pack2(o[8 * k + 0], o[8 * k + 1]),
                          pack2(o[8 * k + 2], o[8 * k + 3]),
                          pack2(o[8 * k + 4], o[8 * k + 5]),
                          pack2(o[8 * k + 6], o[8 * k + 7]));
    q[6] = make_uint4(0u, 0u, 0u, 0u);
    q[7] = make_uint4(0u, 0u, 0u, 0u);

    size_t baseRec = (size_t)blockIdx.x * 256 + wave * 64;
    staged_record_write(lds, q, reinterpret_cast<uint4*>(vtx16),
                        baseRec, kV, wave, lane);
}

__global__ __launch_bounds__(256) void face_kernel16(
    const unsigned* __restrict__ vtx16, const int* __restrict__ faces,
    unsigned* __restrict__ fn16, float* __restrict__ areas)
{
    __shared__ uint4 lds[4][64][8];
    int tid = threadIdx.x;
    int wave = tid >> 6, lane = tid & 63;
    int f = blockIdx.x * 256 + tid;
    bool valid = f < kF;

    float o[48];
#pragma unroll
    for (int i = 0; i < 48; ++i) o[i] = 0.f;

    if (valid) {
        int i0 = faces[3 * f + 0];
        int i1 = faces[3 * f + 1];
        int i2 = faces[3 * f + 2];
        const uint4* r0 = reinterpret_cast<const uint4*>(vtx16 + (size_t)i0 * 32);
        const uint4* r1 = reinterpret_cast<const uint4*>(vtx16 + (size_t)i1 * 32);
        const uint4* r2 = reinterpret_cast<const uint4*>(vtx16 + (size_t)i2 * 32);
#pragma unroll
        for (int g = 0; g < 2; ++g) {
            float A[24], B[24], C[24];
#pragma unroll
            for (int k = 0; k < 3; ++k) {
                uint4 ua = r0[3 * g + k], ub = r1[3 * g + k], uc = r2[3 * g + k];
                float2 t;
                t = unpack2(ua.x); A[8 * k + 0] = t.x; A[8 * k + 1] = t.y;
                t = unpack2(ua.y); A[8 * k + 2] = t.x; A[8 * k + 3] = t.y;
                t = unpack2(ua.z); A[8 * k + 4] = t.x; A[8 * k + 5] = t.y;
                t = unpack2(ua.w); A[8 * k + 6] = t.x; A[8 * k + 7] = t.y;
                t = unpack2(ub.x); B[8 * k + 0] = t.x; B[8 * k + 1] = t.y;
                t = unpack2(ub.y); B[8 * k + 2] = t.x; B[8 * k + 3] = t.y;
                t = unpack2(ub.z); B[8 * k + 4] = t.x; B[8 * k + 5] = t.y;
                t = unpack2(ub.w); B[8 * k + 6] = t.x; B[8 * k + 7] = t.y;
                t = unpack2(uc.x); C[8 * k + 0] = t.x; C[8 * k + 1] = t.y;
                t = unpack2(uc.y); C[8 * k + 2] = t.x; C[8 * k + 3] = t.y;
                t = unpack2(uc.z); C[8 * k + 4] = t.x; C[8 * k + 5] = t.y;
                t = unpack2(uc.w); C[8 * k + 6] = t.x; C[8 * k + 7] = t.y;
            }
#pragma unroll
            for (int bb = 0; bb < 8; ++bb) {
                float x0 = A[3 * bb], y0 = A[3 * bb + 1], z0 = A[3 * bb + 2];
                float x1 = B[3 * bb], y1 = B[3 * bb + 1], z1 = B[3 * bb + 2];
                float x2 = C[3 * bb], y2 = C[3 * bb + 1], z2 = C[3 * bb + 2];
                float e1x = x1 - x0, e1y = y1 - y0, e1z = z1 - z0;
                float e2x = x2 - x1, e2y = y2 - y1, e2z = z2 - z1;
                float nx = cross_comp(e1y, e2z, e1z, e2y);
                float ny = cross_comp(e1z, e2x, e1x, e2z);
                float nz = cross_comp(e1x, e2y, e1y, e2x);
                int bi = 8 * g + bb;
                o[3 * bi + 0] = nx;
                o[3 * bi + 1] = ny;
                o[3 * bi + 2] = nz;
                __builtin_nontemporal_store(
                    0.5f * sqrtf(nx * nx + ny * ny + nz * nz),
                    &areas[(size_t)bi * kF + f]);
            }
        }
    }

    uint4 q[8];
#pragma unroll
    for (int k = 0; k < 6; ++k)
        q[k] = make_uint4(pack2(o[8 * k + 0], o[8 * k + 1]),
                          pack2(o[8 * k + 2], o[8 * k + 3]),
                          pack2(o[8 * k + 4], o[8 * k + 5]),
                          pack2(o[8 * k + 6], o[8 * k + 7]));
    q[6] = make_uint4(0u, 0u, 0u, 0u);
    q[7] = make_uint4(0u, 0u, 0u, 0u);

    size_t baseRec = (size_t)blockIdx.x * 256 + wave * 64;
    staged_record_write(lds, q, reinterpret_cast<uint4*>(fn16),
                        baseRec, kF, wave, lane);
}

__global__ __launch_bounds__(256) void vertex_kernel16(
    const unsigned* __restrict__ fn16, const int* __restrict__ offs,
    const int* __restrict__ adj, float* __restrict__ out)
{
    int v = blockIdx.x * 256 + threadIdx.x;
    if (v >= kV) return;
    int s = offs[v], e = offs[v + 1];

    float acc[48];
#pragma unroll
    for (int i = 0; i < 48; ++i) acc[i] = 0.f;

    for (int j = s; j < e; ++j) {
        const uint4* q = reinterpret_cast<const uint4*>(fn16 + (size_t)adj[j] * 32);
        uint4 w[6];
#pragma unroll
        for (int k = 0; k < 6; ++k) w[k] = q[k];
#pragma unroll
        for (int k = 0; k < 6; ++k) {
            float2 t0 = unpack2(w[k].x), t1 = unpack2(w[k].y);
            float2 t2 = unpack2(w[k].z), t3 = unpack2(w[k].w);
            acc[8 * k + 0] += t0.x; acc[8 * k + 1] += t0.y;
            acc[8 * k + 2] += t1.x; acc[8 * k + 3] += t1.y;
            acc[8 * k + 4] += t2.x; acc[8 * k + 5] += t2.y;
            acc[8 * k + 6] += t3.x; acc[8 * k + 7] += t3.y;
        }
    }

#pragma unroll
    for (int bi = 0; bi < kB; ++bi) {
        float x = acc[3 * bi], y = acc[3 * bi + 1], z = acc[3 * bi + 2];
        float n = sqrtf(x * x + y * y + z * z);
        float inv = 1.0f / fmaxf(n, kEps);
        size_t o = ((size_t)bi * kV + v) * 3;
        __builtin_nontemporal_store(x * inv, &out[o + 0]);
        __builtin_nontemporal_store(y * inv, &out[o + 1]);
        __builtin_nontemporal_store(z * inv, &out[o + 2]);
    }
}

// ---------- R3 fallback (ws >= 16 MB) ----------

__global__ __launch_bounds__(256) void zero_count_kernel(int* __restrict__ count) {
    int i = blockIdx.x * 256 + threadIdx.x;
    if (i < kV) count[i] = 0;
}

__global__ __launch_bounds__(256) void count_kernel(
    const int* __restrict__ faces, int* __restrict__ count)
{
    int i = blockIdx.x * 256 + threadIdx.x;
    if (i >= 3 * kF) return;
    atomicAdd(&count[faces[i]], 1);
}

__global__ __launch_bounds__(256) void fill_adj_kernel(
    const int* __restrict__ faces, const int* __restrict__ offs,
    int* __restrict__ count, int* __restrict__ adj)
{
    int i = blockIdx.x * 256 + threadIdx.x;
    if (i >= 3 * kF) return;
    int v = faces[i];
    int f = i / 3;
    int old = atomicSub(&count[v], 1);
    adj[offs[v] + old - 1] = f;
}

__global__ __launch_bounds__(256) void area_kernel_orig(
    const float* __restrict__ verts, const int* __restrict__ faces,
    float* __restrict__ areas)
{
    int f = blockIdx.x * 256 + threadIdx.x;
    if (f >= kF) return;
    int i0 = faces[3 * f + 0];
    int i1 = faces[3 * f + 1];
    int i2 = faces[3 * f + 2];
    size_t o0 = 3 * (size_t)i0, o1 = 3 * (size_t)i1, o2 = 3 * (size_t)i2;
#pragma unroll
    for (int b = 0; b < kB; ++b) {
        const float* vb = verts + (size_t)b * kV * 3;
        float x0 = vb[o0], y0 = vb[o0 + 1], z0 = vb[o0 + 2];
        float x1 = vb[o1], y1 = vb[o1 + 1], z1 = vb[o1 + 2];
        float x2 = vb[o2], y2 = vb[o2 + 1], z2 = vb[o2 + 2];
        float e1x = x1 - x0, e1y = y1 - y0, e1z = z1 - z0;
        float e2x = x2 - x1, e2y = y2 - y1, e2z = z2 - z1;
        float nx = cross_comp(e1y, e2z, e1z, e2y);
        float ny = cross_comp(e1z, e2x, e1x, e2z);
        float nz = cross_comp(e1x, e2y, e1y, e2x);
        areas[(size_t)b * kF + f] = 0.5f * sqrtf(nx * nx + ny * ny + nz * nz);
    }
}

__global__ __launch_bounds__(256) void gather_normalize_orig(
    const float* __restrict__ verts, const int* __restrict__ faces,
    const int* __restrict__ offs, const int* __restrict__ adj,
    float* __restrict__ out)
{
    int v = blockIdx.x * 256 + threadIdx.x;
    if (v >= kV) return;
    int s = offs[v], e = offs[v + 1];
    float ax[kB], ay[kB], az[kB];
#pragma unroll
    for (int b = 0; b < kB; ++b) { ax[b] = 0.f; ay[b] = 0.f; az[b] = 0.f; }
    for (int j = s; j < e; ++j) {
        int f = adj[j];
        int i0 = faces[3 * f + 0];
        int i1 = faces[3 * f + 1];
        int i2 = faces[3 * f + 2];
        size_t o0 = 3 * (size_t)i0, o1 = 3 * (size_t)i1, o2 = 3 * (size_t)i2;
#pragma unroll
        for (int b = 0; b < kB; ++b) {
            const float* vb = verts + (size_t)b * kV * 3;
            float x0 = vb[o0], y0 = vb[o0 + 1], z0 = vb[o0 + 2];
            float x1 = vb[o1], y1 = vb[o1 + 1], z1 = vb[o1 + 2];
            float x2 = vb[o2], y2 = vb[o2 + 1], z2 = vb[o2 + 2];
            float e1x = x1 - x0, e1y = y1 - y0, e1z = z1 - z0;
            float e2x = x2 - x1, e2y = y2 - y1, e2z = z2 - z1;
            ax[b] += cross_comp(e1y, e2z, e1z, e2y);
            ay[b] += cross_comp(e1z, e2x, e1x, e2z);
            az[b] += cross_comp(e1x, e2y, e1y, e2x);
        }
    }
#pragma unroll
    for (int b = 0; b < kB; ++b) {
        float n = sqrtf(ax[b] * ax[b] + ay[b] * ay[b] + az[b] * az[b]);
        float inv = 1.0f / fmaxf(n, kEps);
        size_t o = ((size_t)b * kV + v) * 3;
        out[o + 0] = ax[b] * inv;
        out[o + 1] = ay[b] * inv;
        out[o + 2] = az[b] * inv;
    }
}

// ---------- R1 fallback ----------

__global__ __launch_bounds__(256) void face_normals_atomic_kernel(
    const float* __restrict__ verts, const int* __restrict__ faces,
    float* __restrict__ vnorm, float* __restrict__ areas)
{
    long long tid = (long long)blockIdx.x * blockDim.x + threadIdx.x;
    if (tid >= (long long)kB * kF) return;
    int f = (int)(tid % kF);
    int b = (int)(tid / kF);
    int i0 = faces[3 * f + 0], i1 = faces[3 * f + 1], i2 = faces[3 * f + 2];
    const float* vb = verts + (size_t)b * kV * 3;
    size_t o0 = 3 * (size_t)i0, o1 = 3 * (size_t)i1, o2 = 3 * (size_t)i2;
    float x0 = vb[o0], y0 = vb[o0 + 1], z0 = vb[o0 + 2];
    float x1 = vb[o1], y1 = vb[o1 + 1], z1 = vb[o1 + 2];
    float x2 = vb[o2], y2 = vb[o2 + 1], z2 = vb[o2 + 2];
    float e1x = x1 - x0, e1y = y1 - y0, e1z = z1 - z0;
    float e2x = x2 - x1, e2y = y2 - y1, e2z = z2 - z1;
    float nx = cross_comp(e1y, e2z, e1z, e2y);
    float ny = cross_comp(e1z, e2x, e1x, e2z);
    float nz = cross_comp(e1x, e2y, e1y, e2x);
    float* vn = vnorm + (size_t)b * kV * 3;
    unsafeAtomicAdd(&vn[o0 + 0], nx); unsafeAtomicAdd(&vn[o0 + 1], ny); unsafeAtomicAdd(&vn[o0 + 2], nz);
    unsafeAtomicAdd(&vn[o1 + 0], nx); unsafeAtomicAdd(&vn[o1 + 1], ny); unsafeAtomicAdd(&vn[o1 + 2], nz);
    unsafeAtomicAdd(&vn[o2 + 0], nx); unsafeAtomicAdd(&vn[o2 + 1], ny); unsafeAtomicAdd(&vn[o2 + 2], nz);
    areas[(size_t)b * kF + f] = 0.5f * sqrtf(nx * nx + ny * ny + nz * nz);
}

__global__ __launch_bounds__(256) void normalize_inplace_kernel(float* __restrict__ vnorm) {
    long long tid = (long long)blockIdx.x * blockDim.x + threadIdx.x;
    if (tid >= (long long)kB * kV) return;
    size_t o = 3 * (size_t)tid;
    float x = vnorm[o], y = vnorm[o + 1], z = vnorm[o + 2];
    float n = sqrtf(x * x + y * y + z * z);
    float inv = 1.0f / fmaxf(n, kEps);
    vnorm[o] = x * inv; vnorm[o + 1] = y * inv; vnorm[o + 2] = z * inv;
}

// ---------- launch ----------

static void build_csr(const int* faces, int* count, int* offs, int* blockSums,
                      int* adj, hipStream_t stream) {
    int gInc = (3 * kF + 255) / 256;
    zero_count_kernel<<<kNB, 256, 0, stream>>>(count);
    count_kernel<<<gInc, 256, 0, stream>>>(faces, count);
    scan_block_kernel<<<kNB, 256, 0, stream>>>(count, offs, blockSums);
    scan_sums_kernel<<<1, 256, 0, stream>>>(blockSums);
    add_offsets_kernel<<<(kV + 1 + 255) / 256, 256, 0, stream>>>(offs, blockSums);
    fill_adj_kernel<<<gInc, 256, 0, stream>>>(faces, offs, count, adj);
    sort_rows_kernel<<<kNB, 256, 0, stream>>>(offs, adj);
}

extern "C" void kernel_launch(void* const* d_in, const int* in_sizes, int n_in,
                              void* d_out, int out_size, void* d_ws, size_t ws_size,
                              hipStream_t stream) {
    const float* verts = (const float*)d_in[0];
    const int*   faces = (const int*)d_in[1];

    float* out   = (float*)d_out;
    float* vecs  = out;                               // B*V*3
    float* areas = out + (size_t)kB * kV * 3;         // B*F

    int gF = (kF + 255) / 256;

    if (ws_size >= kWsMain) {
        unsigned* vtx16 = (unsigned*)d_ws;                    // 64 MB
        unsigned* fn16  = vtx16 + kVtx16Uints;                // 128 MB
        uint2*    inc   = (uint2*)(fn16 + kFn16Uints);        // 24 MB
        int* count      = (int*)(inc + kIncPairs);
        int* offs       = count + kV;
        int* blockSums  = offs + (kV + 1);
        int* adj        = blockSums + kNB;
        int* bh         = adj + 3 * (size_t)kF;               // kBhN
        int* regionBase = bh + kBhN;                          // kNR+1
        int* regionSum  = regionBase + (kNR + 1);             // kNR

        a1_hist_kernel<<<kNBlkA, 256, 0, stream>>>(faces, bh);
        s1_region_scan_kernel<<<kNR, 256, 0, stream>>>(bh, regionSum);
        s2_base_scan_kernel<<<1, 256, 0, stream>>>(regionSum, regionBase);
        a3_scatter_kernel<<<kNBlkA, 256, 0, stream>>>(faces, bh, regionBase, inc);
        k1_count_kernel<<<kNR, 1024, 0, stream>>>(inc, regionBase, count);
        scan_block_kernel<<<kNB, 256, 0, stream>>>(count, offs, blockSums);
        scan_sums_kernel<<<1, 256, 0, stream>>>(blockSums);
        add_offsets_kernel<<<(kV + 1 + 255) / 256, 256, 0, stream>>>(offs, blockSums);
        k3_fill_kernel<<<kNR, 1024, 0, stream>>>(inc, regionBase, offs, adj);
        sort_rows_kernel<<<kNB, 256, 0, stream>>>(offs, adj);

        transpose_kernel16<<<kNB, 256, 0, stream>>>(verts, vtx16);
        face_kernel16<<<gF, 256, 0, stream>>>(vtx16, faces, fn16, areas);
        vertex_kernel16<<<kNB, 256, 0, stream>>>(fn16, offs, adj, vecs);
    } else if (ws_size >= kWsC) {
        int* count     = (int*)d_ws;
        int* offs      = count + kV;
        int* blockSums = offs + (kV + 1);
        int* adj       = blockSums + kNB;

        build_csr(faces, count, offs, blockSums, adj, stream);
        area_kernel_orig<<<gF, 256, 0, stream>>>(verts, faces, areas);
        gather_normalize_orig<<<kNB, 256, 0, stream>>>(verts, faces, offs, adj, vecs);
    } else {
        (void)hipMemsetAsync(vecs, 0, (size_t)kB * kV * 3 * sizeof(float), stream);
        long long nf = (long long)kB * kF;
        face_normals_atomic_kernel<<<(int)((nf + 255) / 256), 256, 0, stream>>>(verts, faces, vecs, areas);
        long long nv = (long long)kB * kV;
        normalize_inplace_kernel<<<(int)((nv + 255) / 256), 256, 0, stream>>>(vecs);
    }
}

// Round 15
// 339.746 us; speedup vs baseline: 34.9659x; 1.0103x over previous
//
#include <hip/hip_runtime.h>
#include <hip/hip_fp16.h>
#include <math.h>

namespace {
constexpr int kB = 16;
constexpr int kV = 500000;
constexpr int kF = 1000000;
constexpr float kEps = 1e-6f;
constexpr int kNB = (kV + 255) / 256;       // 1954

// region partition for LDS-local CSR build
constexpr int kRegBits = 12;                 // 4096 vertices / region
constexpr int kRegSize = 1 << kRegBits;
constexpr int kNR   = (kV + kRegSize - 1) / kRegSize;   // 123
constexpr int kNBlkA = (3 * kF + 3071) / 3072;          // 977 (3072 items/blk)
constexpr int kBhN  = kNR * kNBlkA;                      // 120171

constexpr size_t kVtx16Uints = (size_t)kV * 32;    // 64 MB  (128 B records)
constexpr size_t kFn16Uints  = (size_t)kF * 32;    // 128 MB (128 B records)
constexpr size_t kIncPairs   = 3 * (size_t)kF;     // 24 MB (uint2)
constexpr size_t kIntWords   = (size_t)kV + (kV + 1) + kNB + 3 * (size_t)kF
                             + kBhN + (kNR + 1) + kNR;
constexpr size_t kWsMain = (kVtx16Uints + kFn16Uints) * 4 + kIncPairs * 8
                         + kIntWords * 4;          // ~232.5 MB
constexpr size_t kWsC    = ((size_t)kV + (kV + 1) + kNB + 3 * (size_t)kF) * 4;
}

typedef unsigned u32x4 __attribute__((ext_vector_type(4)));

// a*b - c*d unfused: degenerate faces cancel EXACTLY (matches numpy; the
// fp16-rounded coords of duplicate indices are identical, so e2 = -e1 and
// both products round identically). FMA contraction would leave ulp noise
// that normalization amplifies to O(1).
__device__ __forceinline__ float cross_comp(float a, float b, float c, float d) {
    return __fsub_rn(__fmul_rn(a, b), __fmul_rn(c, d));
}

__device__ __forceinline__ unsigned pack2(float a, float b) {
    __half2 h = __halves2half2(__float2half_rn(a), __float2half_rn(b));
    return __builtin_bit_cast(unsigned, h);
}
__device__ __forceinline__ float2 unpack2(unsigned u) {
    return __half22float2(__builtin_bit_cast(__half2, u));
}

// Stage 64 records/wave (8 KB) in LDS, then write out 1 KB contiguous per
// iteration -> every store instruction covers full 128 B lines, no RFO.
// PLAIN variant: cached — used for vtx16 (the table must be L3-resident
// for the face pass's random gathers).
__device__ __forceinline__ void staged_record_write(
    uint4 lds[4][64][8], const uint4 q[8], uint4* __restrict__ dstBase,
    size_t baseRec, int maxRec, int wave, int lane)
{
#pragma unroll
    for (int k = 0; k < 8; ++k)
        lds[wave][lane][(k + lane) & 7] = q[k];
    __syncthreads();
    uint4* dst = dstBase + baseRec * 8;
#pragma unroll
    for (int k = 0; k < 8; ++k) {
        int g = k * 64 + lane;
        int r = g >> 3, w = g & 7;
        if (baseRec + (size_t)r < (size_t)maxRec)
            dst[g] = lds[wave][r][(w + r) & 7];
    }
}

// NT variant: bypass/minimize cache for the fn16 write stream so it does
// NOT evict the vtx16 gather table during the face pass. fn16 is re-read
// by the vertex pass, but it fits L3 (128 MB) with ~3x reuse there.
__device__ __forceinline__ void staged_record_write_nt(
    uint4 lds[4][64][8], const uint4 q[8], uint4* __restrict__ dstBase,
    size_t baseRec, int maxRec, int wave, int lane)
{
#pragma unroll
    for (int k = 0; k < 8; ++k)
        lds[wave][lane][(k + lane) & 7] = q[k];
    __syncthreads();
    uint4* dst = dstBase + baseRec * 8;
#pragma unroll
    for (int k = 0; k < 8; ++k) {
        int g = k * 64 + lane;
        int r = g >> 3, w = g & 7;
        if (baseRec + (size_t)r < (size_t)maxRec) {
            uint4 val = lds[wave][r][(w + r) & 7];
            u32x4 nv; nv.x = val.x; nv.y = val.y; nv.z = val.z; nv.w = val.w;
            __builtin_nontemporal_store(nv, reinterpret_cast<u32x4*>(&dst[g]));
        }
    }
}

// ---------- scan helper ----------

__device__ __forceinline__ int block_incl_scan256(int x, int* lds) {
    int lane = threadIdx.x & 63;
    int wave = threadIdx.x >> 6;
    for (int d = 1; d < 64; d <<= 1) {
        int y = __shfl_up(x, d, 64);
        if (lane >= d) x += y;
    }
    if (lane == 63) lds[wave] = x;
    __syncthreads();
    int add = 0;
    for (int w = 0; w < wave; ++w) add += lds[w];
    __syncthreads();
    return x + add;
}

// ---------- CSR build: LDS-local, no global data atomics ----------

__global__ __launch_bounds__(256) void a1_hist_kernel(
    const int* __restrict__ faces, int* __restrict__ bh)
{
    __shared__ int h[kNR];
    int tid = threadIdx.x;
    for (int j = tid; j < kNR; j += 256) h[j] = 0;
    __syncthreads();
    size_t base = (size_t)blockIdx.x * 3072;
#pragma unroll
    for (int k = 0; k < 12; ++k) {
        size_t i = base + (size_t)k * 256 + tid;
        if (i < (size_t)3 * kF) atomicAdd(&h[faces[i] >> kRegBits], 1);
    }
    __syncthreads();
    for (int j = tid; j < kNR; j += 256)
        bh[(size_t)j * kNBlkA + blockIdx.x] = h[j];
}

// S1: per-region EXCLUSIVE scan of bh row (977 entries), 123 parallel blocks.
__global__ __launch_bounds__(256) void s1_region_scan_kernel(
    int* __restrict__ bh, int* __restrict__ regionSum)
{
    __shared__ int lds[4];
    __shared__ int carry;
    int r = blockIdx.x;
    int tid = threadIdx.x;
    if (tid == 0) carry = 0;
    __syncthreads();
    size_t base = (size_t)r * kNBlkA;
    for (int off = 0; off < kNBlkA; off += 256) {
        int idx = off + tid;
        int x = (idx < kNBlkA) ? bh[base + idx] : 0;
        int incl = block_incl_scan256(x, lds);
        int c = carry;
        __syncthreads();
        if (idx < kNBlkA) bh[base + idx] = incl - x + c;   // exclusive-in-region
        if (tid == 255) carry = c + incl;
        __syncthreads();
    }
    if (tid == 0) regionSum[r] = carry;
}

// S2: tiny scan of 123 region totals -> regionBase (exclusive).
__global__ __launch_bounds__(256) void s2_base_scan_kernel(
    const int* __restrict__ regionSum, int* __restrict__ regionBase)
{
    __shared__ int lds[4];
    int tid = threadIdx.x;
    int x = (tid < kNR) ? regionSum[tid] : 0;
    int incl = block_incl_scan256(x, lds);
    if (tid < kNR) regionBase[tid] = incl - x;
    if (tid == 0) regionBase[kNR] = 3 * kF;
}

// A3: scatter (v,f) pairs region-major using per-(blk,region) cursors
// (bh + regionBase folded in) + LDS slots. No global atomics.
__global__ __launch_bounds__(256) void a3_scatter_kernel(
    const int* __restrict__ faces, const int* __restrict__ bh,
    const int* __restrict__ regionBase, uint2* __restrict__ inc)
{
    __shared__ int cur[kNR];
    int tid = threadIdx.x;
    for (int j = tid; j < kNR; j += 256)
        cur[j] = bh[(size_t)j * kNBlkA + blockIdx.x] + regionBase[j];
    __syncthreads();
    size_t base = (size_t)blockIdx.x * 3072;
#pragma unroll
    for (int k = 0; k < 12; ++k) {
        size_t i = base + (size_t)k * 256 + tid;
        if (i < (size_t)3 * kF) {
            int v = faces[i];
            int f = (int)(i / 3);
            int pos = atomicAdd(&cur[v >> kRegBits], 1);
            inc[pos] = make_uint2((unsigned)v, (unsigned)f);
        }
    }
}

// K1: one block per region; LDS histogram (16 KB); coalesced count write.
__global__ __launch_bounds__(1024) void k1_count_kernel(
    const uint2* __restrict__ inc, const int* __restrict__ regionBase,
    int* __restrict__ count)
{
    __shared__ int h[kRegSize];
    int tid = threadIdx.x;
    int r = blockIdx.x;
    for (int j = tid; j < kRegSize; j += 1024) h[j] = 0;
    __syncthreads();
    int s = regionBase[r], e = regionBase[r + 1];
    for (int j = s + tid; j < e; j += 1024)
        atomicAdd(&h[inc[j].x & (kRegSize - 1)], 1);
    __syncthreads();
    int vbase = r << kRegBits;
    for (int j = tid; j < kRegSize; j += 1024) {
        int v = vbase + j;
        if (v < kV) count[v] = h[j];
    }
}

__global__ __launch_bounds__(256) void scan_block_kernel(
    const int* __restrict__ count, int* __restrict__ offs,
    int* __restrict__ blockSums)
{
    __shared__ int lds[4];
    int i = blockIdx.x * 256 + threadIdx.x;
    int x = (i < kV) ? count[i] : 0;
    int incl = block_incl_scan256(x, lds);
    if (i < kV) offs[i] = incl - x;
    if (threadIdx.x == 255) blockSums[blockIdx.x] = incl;
}

__global__ __launch_bounds__(256) void scan_sums_kernel(int* __restrict__ blockSums) {
    __shared__ int lds[4];
    __shared__ int carry;
    if (threadIdx.x == 0) carry = 0;
    __syncthreads();
    for (int base = 0; base < kNB; base += 256) {
        int i = base + threadIdx.x;
        int x = (i < kNB) ? blockSums[i] : 0;
        int incl = block_incl_scan256(x, lds);
        int c = carry;
        __syncthreads();
        if (i < kNB) blockSums[i] = incl - x + c;
        if (threadIdx.x == 255) carry = c + incl;
        __syncthreads();
    }
}

__global__ __launch_bounds__(256) void add_offsets_kernel(
    int* __restrict__ offs, const int* __restrict__ blockSums)
{
    int i = blockIdx.x * 256 + threadIdx.x;
    if (i < kV) offs[i] += blockSums[i >> 8];
    if (i == kV) offs[kV] = 3 * kF;
}

// K3: one block per region; LDS cursors; adj writes in an L2-resident slice.
__global__ __launch_bounds__(1024) void k3_fill_kernel(
    const uint2* __restrict__ inc, const int* __restrict__ regionBase,
    const int* __restrict__ offs, int* __restrict__ adj)
{
    __shared__ int cur[kRegSize];
    int tid = threadIdx.x;
    int r = blockIdx.x;
    for (int j = tid; j < kRegSize; j += 1024) cur[j] = 0;
    __syncthreads();
    int s = regionBase[r], e = regionBase[r + 1];
    for (int j = s + tid; j < e; j += 1024) {
        uint2 p = inc[j];
        int v = (int)p.x;
        int slot = atomicAdd(&cur[v & (kRegSize - 1)], 1);
        adj[offs[v] + slot] = (int)p.y;
    }
}

// canonicalize slot order -> bitwise-deterministic adj -> deterministic fp sums
__global__ __launch_bounds__(256) void sort_rows_kernel(
    const int* __restrict__ offs, int* __restrict__ adj)
{
    int v = blockIdx.x * 256 + threadIdx.x;
    if (v >= kV) return;
    int s = offs[v], e = offs[v + 1];
    for (int i = s + 1; i < e; ++i) {
        int key = adj[i];
        int j = i - 1;
        while (j >= s && adj[j] > key) { adj[j + 1] = adj[j]; --j; }
        adj[j + 1] = key;
    }
}

// ---------- fp16 128 B record pipeline ----------

__global__ __launch_bounds__(256) void transpose_kernel16(
    const float* __restrict__ verts, unsigned* __restrict__ vtx16)
{
    __shared__ uint4 lds[4][64][8];
    int tid = threadIdx.x;
    int wave = tid >> 6, lane = tid & 63;
    int v = blockIdx.x * 256 + tid;
    bool valid = v < kV;

    float o[48];
#pragma unroll
    for (int i = 0; i < 48; ++i) o[i] = 0.f;
    if (valid) {
#pragma unroll
        for (int b = 0; b < kB; ++b) {
            const float* p = verts + ((size_t)b * kV + v) * 3;
            o[3 * b + 0] = p[0];
            o[3 * b + 1] = p[1];
            o[3 * b + 2] = p[2];
        }
    }
    uint4 q[8];
#pragma unroll
    for (int k = 0; k < 6; ++k)
        q[k] = make_uint4(pack2(o[8 * k + 0], o[8 * k + 1]),
                          pack2(o[8 * k + 2], o[8 * k + 3]),
                          pack2(o[8 * k + 4], o[8 * k + 5]),
                          pack2(o[8 * k + 6], o[8 * k + 7]));
    q[6] = make_uint4(0u, 0u, 0u, 0u);
    q[7] = make_uint4(0u, 0u, 0u, 0u);

    size_t baseRec = (size_t)blockIdx.x * 256 + wave * 64;
    staged_record_write(lds, q, reinterpret_cast<uint4*>(vtx16),
                        baseRec, kV, wave, lane);          // cached: table
}

__global__ __launch_bounds__(256) void face_kernel16(
    const unsigned* __restrict__ vtx16, const int* __restrict__ faces,
    unsigned* __restrict__ fn16, float* __restrict__ areas)
{
    __shared__ uint4 lds[4][64][8];
    int tid = threadIdx.x;
    int wave = tid >> 6, lane = tid & 63;
    int f = blockIdx.x * 256 + tid;
    bool valid = f < kF;

    float o[48];
#pragma unroll
    for (int i = 0; i < 48; ++i) o[i] = 0.f;

    if (valid) {
        int i0 = faces[3 * f + 0];
        int i1 = faces[3 * f + 1];
        int i2 = faces[3 * f + 2];
        const uint4* r0 = reinterpret_cast<const uint4*>(vtx16 + (size_t)i0 * 32);
        const uint4* r1 = reinterpret_cast<const uint4*>(vtx16 + (size_t)i1 * 32);
        const uint4* r2 = reinterpret_cast<const uint4*>(vtx16 + (size_t)i2 * 32);
#pragma unroll
        for (int g = 0; g < 2; ++g) {
            float A[24], B[24], C[24];
#pragma unroll
            for (int k = 0; k < 3; ++k) {
                uint4 ua = r0[3 * g + k], ub = r1[3 * g + k], uc = r2[3 * g + k];
                float2 t;
                t = unpack2(ua.x); A[8 * k + 0] = t.x; A[8 * k + 1] = t.y;
                t = unpack2(ua.y); A[8 * k + 2] = t.x; A[8 * k + 3] = t.y;
                t = unpack2(ua.z); A[8 * k + 4] = t.x; A[8 * k + 5] = t.y;
                t = unpack2(ua.w); A[8 * k + 6] = t.x; A[8 * k + 7] = t.y;
                t = unpack2(ub.x); B[8 * k + 0] = t.x; B[8 * k + 1] = t.y;
                t = unpack2(ub.y); B[8 * k + 2] = t.x; B[8 * k + 3] = t.y;
                t = unpack2(ub.z); B[8 * k + 4] = t.x; B[8 * k + 5] = t.y;
                t = unpack2(ub.w); B[8 * k + 6] = t.x; B[8 * k + 7] = t.y;
                t = unpack2(uc.x); C[8 * k + 0] = t.x; C[8 * k + 1] = t.y;
                t = unpack2(uc.y); C[8 * k + 2] = t.x; C[8 * k + 3] = t.y;
                t = unpack2(uc.z); C[8 * k + 4] = t.x; C[8 * k + 5] = t.y;
                t = unpack2(uc.w); C[8 * k + 6] = t.x; C[8 * k + 7] = t.y;
            }
#pragma unroll
            for (int bb = 0; bb < 8; ++bb) {
                float x0 = A[3 * bb], y0 = A[3 * bb + 1], z0 = A[3 * bb + 2];
                float x1 = B[3 * bb], y1 = B[3 * bb + 1], z1 = B[3 * bb + 2];
                float x2 = C[3 * bb], y2 = C[3 * bb + 1], z2 = C[3 * bb + 2];
                float e1x = x1 - x0, e1y = y1 - y0, e1z = z1 - z0;
                float e2x = x2 - x1, e2y = y2 - y1, e2z = z2 - z1;
                float nx = cross_comp(e1y, e2z, e1z, e2y);
                float ny = cross_comp(e1z, e2x, e1x, e2z);
                float nz = cross_comp(e1x, e2y, e1y, e2x);
                int bi = 8 * g + bb;
                o[3 * bi + 0] = nx;
                o[3 * bi + 1] = ny;
                o[3 * bi + 2] = nz;
                __builtin_nontemporal_store(
                    0.5f * sqrtf(nx * nx + ny * ny + nz * nz),
                    &areas[(size_t)bi * kF + f]);
            }
        }
    }

    uint4 q[8];
#pragma unroll
    for (int k = 0; k < 6; ++k)
        q[k] = make_uint4(pack2(o[8 * k + 0], o[8 * k + 1]),
                          pack2(o[8 * k + 2], o[8 * k + 3]),
                          pack2(o[8 * k + 4], o[8 * k + 5]),
                          pack2(o[8 * k + 6], o[8 * k + 7]));
    q[6] = make_uint4(0u, 0u, 0u, 0u);
    q[7] = make_uint4(0u, 0u, 0u, 0u);

    size_t baseRec = (size_t)blockIdx.x * 256 + wave * 64;
    staged_record_write_nt(lds, q, reinterpret_cast<uint4*>(fn16),
                           baseRec, kF, wave, lane);   // NT: keep vtx16 in L3
}

__global__ __launch_bounds__(256) void vertex_kernel16(
    const unsigned* __restrict__ fn16, const int* __restrict__ offs,
    const int* __restrict__ adj, float* __restrict__ out)
{
    int v = blockIdx.x * 256 + threadIdx.x;
    if (v >= kV) return;
    int s = offs[v], e = offs[v + 1];

    float acc[48];
#pragma unroll
    for (int i = 0; i < 48; ++i) acc[i] = 0.f;

    for (int j = s; j < e; ++j) {
        const uint4* q = reinterpret_cast<const uint4*>(fn16 + (size_t)adj[j] * 32);
        uint4 w[6];
#pragma unroll
        for (int k = 0; k < 6; ++k) w[k] = q[k];
#pragma unroll
        for (int k = 0; k < 6; ++k) {
            float2 t0 = unpack2(w[k].x), t1 = unpack2(w[k].y);
            float2 t2 = unpack2(w[k].z), t3 = unpack2(w[k].w);
            acc[8 * k + 0] += t0.x; acc[8 * k + 1] += t0.y;
            acc[8 * k + 2] += t1.x; acc[8 * k + 3] += t1.y;
            acc[8 * k + 4] += t2.x; acc[8 * k + 5] += t2.y;
            acc[8 * k + 6] += t3.x; acc[8 * k + 7] += t3.y;
        }
    }

#pragma unroll
    for (int bi = 0; bi < kB; ++bi) {
        float x = acc[3 * bi], y = acc[3 * bi + 1], z = acc[3 * bi + 2];
        float n = sqrtf(x * x + y * y + z * z);
        float inv = 1.0f / fmaxf(n, kEps);
        size_t o = ((size_t)bi * kV + v) * 3;
        __builtin_nontemporal_store(x * inv, &out[o + 0]);
        __builtin_nontemporal_store(y * inv, &out[o + 1]);
        __builtin_nontemporal_store(z * inv, &out[o + 2]);
    }
}

// ---------- R3 fallback (ws >= 16 MB) ----------

__global__ __launch_bounds__(256) void zero_count_kernel(int* __restrict__ count) {
    int i = blockIdx.x * 256 + threadIdx.x;
    if (i < kV) count[i] = 0;
}

__global__ __launch_bounds__(256) void count_kernel(
    const int* __restrict__ faces, int* __restrict__ count)
{
    int i = blockIdx.x * 256 + threadIdx.x;
    if (i >= 3 * kF) return;
    atomicAdd(&count[faces[i]], 1);
}

__global__ __launch_bounds__(256) void fill_adj_kernel(
    const int* __restrict__ faces, const int* __restrict__ offs,
    int* __restrict__ count, int* __restrict__ adj)
{
    int i = blockIdx.x * 256 + threadIdx.x;
    if (i >= 3 * kF) return;
    int v = faces[i];
    int f = i / 3;
    int old = atomicSub(&count[v], 1);
    adj[offs[v] + old - 1] = f;
}

__global__ __launch_bounds__(256) void area_kernel_orig(
    const float* __restrict__ verts, const int* __restrict__ faces,
    float* __restrict__ areas)
{
    int f = blockIdx.x * 256 + threadIdx.x;
    if (f >= kF) return;
    int i0 = faces[3 * f + 0];
    int i1 = faces[3 * f + 1];
    int i2 = faces[3 * f + 2];
    size_t o0 = 3 * (size_t)i0, o1 = 3 * (size_t)i1, o2 = 3 * (size_t)i2;
#pragma unroll
    for (int b = 0; b < kB; ++b) {
        const float* vb = verts + (size_t)b * kV * 3;
        float x0 = vb[o0], y0 = vb[o0 + 1], z0 = vb[o0 + 2];
        float x1 = vb[o1], y1 = vb[o1 + 1], z1 = vb[o1 + 2];
        float x2 = vb[o2], y2 = vb[o2 + 1], z2 = vb[o2 + 2];
        float e1x = x1 - x0, e1y = y1 - y0, e1z = z1 - z0;
        float e2x = x2 - x1, e2y = y2 - y1, e2z = z2 - z1;
        float nx = cross_comp(e1y, e2z, e1z, e2y);
        float ny = cross_comp(e1z, e2x, e1x, e2z);
        float nz = cross_comp(e1x, e2y, e1y, e2x);
        areas[(size_t)b * kF + f] = 0.5f * sqrtf(nx * nx + ny * ny + nz * nz);
    }
}

__global__ __launch_bounds__(256) void gather_normalize_orig(
    const float* __restrict__ verts, const int* __restrict__ faces,
    const int* __restrict__ offs, const int* __restrict__ adj,
    float* __restrict__ out)
{
    int v = blockIdx.x * 256 + threadIdx.x;
    if (v >= kV) return;
    int s = offs[v], e = offs[v + 1];
    float ax[kB], ay[kB], az[kB];
#pragma unroll
    for (int b = 0; b < kB; ++b) { ax[b] = 0.f; ay[b] = 0.f; az[b] = 0.f; }
    for (int j = s; j < e; ++j) {
        int f = adj[j];
        int i0 = faces[3 * f + 0];
        int i1 = faces[3 * f + 1];
        int i2 = faces[3 * f + 2];
        size_t o0 = 3 * (size_t)i0, o1 = 3 * (size_t)i1, o2 = 3 * (size_t)i2;
#pragma unroll
        for (int b = 0; b < kB; ++b) {
            const float* vb = verts + (size_t)b * kV * 3;
            float x0 = vb[o0], y0 = vb[o0 + 1], z0 = vb[o0 + 2];
            float x1 = vb[o1], y1 = vb[o1 + 1], z1 = vb[o1 + 2];
            float x2 = vb[o2], y2 = vb[o2 + 1], z2 = vb[o2 + 2];
            float e1x = x1 - x0, e1y = y1 - y0, e1z = z1 - z0;
            float e2x = x2 - x1, e2y = y2 - y1, e2z = z2 - z1;
            ax[b] += cross_comp(e1y, e2z, e1z, e2y);
            ay[b] += cross_comp(e1z, e2x, e1x, e2z);
            az[b] += cross_comp(e1x, e2y, e1y, e2x);
        }
    }
#pragma unroll
    for (int b = 0; b < kB; ++b) {
        float n = sqrtf(ax[b] * ax[b] + ay[b] * ay[b] + az[b] * az[b]);
        float inv = 1.0f / fmaxf(n, kEps);
        size_t o = ((size_t)b * kV + v) * 3;
        out[o + 0] = ax[b] * inv;
        out[o + 1] = ay[b] * inv;
        out[o + 2] = az[b] * inv;
    }
}

// ---------- R1 fallback ----------

__global__ __launch_bounds__(256) void face_normals_atomic_kernel(
    const float* __restrict__ verts, const int* __restrict__ faces,
    float* __restrict__ vnorm, float* __restrict__ areas)
{
    long long tid = (long long)blockIdx.x * blockDim.x + threadIdx.x;
    if (tid >= (long long)kB * kF) return;
    int f = (int)(tid % kF);
    int b = (int)(tid / kF);
    int i0 = faces[3 * f + 0], i1 = faces[3 * f + 1], i2 = faces[3 * f + 2];
    const float* vb = verts + (size_t)b * kV * 3;
    size_t o0 = 3 * (size_t)i0, o1 = 3 * (size_t)i1, o2 = 3 * (size_t)i2;
    float x0 = vb[o0], y0 = vb[o0 + 1], z0 = vb[o0 + 2];
    float x1 = vb[o1], y1 = vb[o1 + 1], z1 = vb[o1 + 2];
    float x2 = vb[o2], y2 = vb[o2 + 1], z2 = vb[o2 + 2];
    float e1x = x1 - x0, e1y = y1 - y0, e1z = z1 - z0;
    float e2x = x2 - x1, e2y = y2 - y1, e2z = z2 - z1;
    float nx = cross_comp(e1y, e2z, e1z, e2y);
    float ny = cross_comp(e1z, e2x, e1x, e2z);
    float nz = cross_comp(e1x, e2y, e1y, e2x);
    float* vn = vnorm + (size_t)b * kV * 3;
    unsafeAtomicAdd(&vn[o0 + 0], nx); unsafeAtomicAdd(&vn[o0 + 1], ny); unsafeAtomicAdd(&vn[o0 + 2], nz);
    unsafeAtomicAdd(&vn[o1 + 0], nx); unsafeAtomicAdd(&vn[o1 + 1], ny); unsafeAtomicAdd(&vn[o1 + 2], nz);
    unsafeAtomicAdd(&vn[o2 + 0], nx); unsafeAtomicAdd(&vn[o2 + 1], ny); unsafeAtomicAdd(&vn[o2 + 2], nz);
    areas[(size_t)b * kF + f] = 0.5f * sqrtf(nx * nx + ny * ny + nz * nz);
}

__global__ __launch_bounds__(256) void normalize_inplace_kernel(float* __restrict__ vnorm) {
    long long tid = (long long)blockIdx.x * blockDim.x + threadIdx.x;
    if (tid >= (long long)kB * kV) return;
    size_t o = 3 * (size_t)tid;
    float x = vnorm[o], y = vnorm[o + 1], z = vnorm[o + 2];
    float n = sqrtf(x * x + y * y + z * z);
    float inv = 1.0f / fmaxf(n, kEps);
    vnorm[o] = x * inv; vnorm[o + 1] = y * inv; vnorm[o + 2] = z * inv;
}

// ---------- launch ----------

static void build_csr(const int* faces, int* count, int* offs, int* blockSums,
                      int* adj, hipStream_t stream) {
    int gInc = (3 * kF + 255) / 256;
    zero_count_kernel<<<kNB, 256, 0, stream>>>(count);
    count_kernel<<<gInc, 256, 0, stream>>>(faces, count);
    scan_block_kernel<<<kNB, 256, 0, stream>>>(count, offs, blockSums);
    scan_sums_kernel<<<1, 256, 0, stream>>>(blockSums);
    add_offsets_kernel<<<(kV + 1 + 255) / 256, 256, 0, stream>>>(offs, blockSums);
    fill_adj_kernel<<<gInc, 256, 0, stream>>>(faces, offs, count, adj);
    sort_rows_kernel<<<kNB, 256, 0, stream>>>(offs, adj);
}

extern "C" void kernel_launch(void* const* d_in, const int* in_sizes, int n_in,
                              void* d_out, int out_size, void* d_ws, size_t ws_size,
                              hipStream_t stream) {
    const float* verts = (const float*)d_in[0];
    const int*   faces = (const int*)d_in[1];

    float* out   = (float*)d_out;
    float* vecs  = out;                               // B*V*3
    float* areas = out + (size_t)kB * kV * 3;         // B*F

    int gF = (kF + 255) / 256;

    if (ws_size >= kWsMain) {
        unsigned* vtx16 = (unsigned*)d_ws;                    // 64 MB
        unsigned* fn16  = vtx16 + kVtx16Uints;                // 128 MB
        uint2*    inc   = (uint2*)(fn16 + kFn16Uints);        // 24 MB
        int* count      = (int*)(inc + kIncPairs);
        int* offs       = count + kV;
        int* blockSums  = offs + (kV + 1);
        int* adj        = blockSums + kNB;
        int* bh         = adj + 3 * (size_t)kF;               // kBhN
        int* regionBase = bh + kBhN;                          // kNR+1
        int* regionSum  = regionBase + (kNR + 1);             // kNR

        a1_hist_kernel<<<kNBlkA, 256, 0, stream>>>(faces, bh);
        s1_region_scan_kernel<<<kNR, 256, 0, stream>>>(bh, regionSum);
        s2_base_scan_kernel<<<1, 256, 0, stream>>>(regionSum, regionBase);
        a3_scatter_kernel<<<kNBlkA, 256, 0, stream>>>(faces, bh, regionBase, inc);
        k1_count_kernel<<<kNR, 1024, 0, stream>>>(inc, regionBase, count);
        scan_block_kernel<<<kNB, 256, 0, stream>>>(count, offs, blockSums);
        scan_sums_kernel<<<1, 256, 0, stream>>>(blockSums);
        add_offsets_kernel<<<(kV + 1 + 255) / 256, 256, 0, stream>>>(offs, blockSums);
        k3_fill_kernel<<<kNR, 1024, 0, stream>>>(inc, regionBase, offs, adj);
        sort_rows_kernel<<<kNB, 256, 0, stream>>>(offs, adj);

        transpose_kernel16<<<kNB, 256, 0, stream>>>(verts, vtx16);
        face_kernel16<<<gF, 256, 0, stream>>>(vtx16, faces, fn16, areas);
        vertex_kernel16<<<kNB, 256, 0, stream>>>(fn16, offs, adj, vecs);
    } else if (ws_size >= kWsC) {
        int* count     = (int*)d_ws;
        int* offs      = count + kV;
        int* blockSums = offs + (kV + 1);
        int* adj       = blockSums + kNB;

        build_csr(faces, count, offs, blockSums, adj, stream);
        area_kernel_orig<<<gF, 256, 0, stream>>>(verts, faces, areas);
        gather_normalize_orig<<<kNB, 256, 0, stream>>>(verts, faces, offs, adj, vecs);
    } else {
        (void)hipMemsetAsync(vecs, 0, (size_t)kB * kV * 3 * sizeof(float), stream);
        long long nf = (long long)kB * kF;
        face_normals_atomic_kernel<<<(int)((nf + 255) / 256), 256, 0, stream>>>(verts, faces, vecs, areas);
        long long nv = (long long)kB * kV;
        normalize_inplace_kernel<<<(int)((nv + 255) / 256), 256, 0, stream>>>(vecs);
    }
}